// Round 1
// baseline (955.353 us; speedup 1.0000x reference)
//
#include <hip/hip_runtime.h>

#define N_NODES 50000
#define N_EDGES 1600000
#define F_IN    128
#define EMB     48
#define HID     48
#define OUTF    64
#define KCH     7

// ---------------- degree (by row) + in-degree histogram (by col) ----------------
__global__ __launch_bounds__(256) void deg_hist_kernel(
    const int* __restrict__ row, const int* __restrict__ col,
    const float* __restrict__ w, float* __restrict__ deg, int* __restrict__ cnt)
{
    int i = blockIdx.x * blockDim.x + threadIdx.x;
    int stride = gridDim.x * blockDim.x;
    for (; i < N_EDGES; i += stride) {
        atomicAdd(&deg[row[i]], w[i]);
        atomicAdd(&cnt[col[i]], 1);
    }
}

// ---------------- dinv = deg>0 ? rsqrt(deg) : 0 (in place) ----------------
__global__ __launch_bounds__(256) void dinv_kernel(float* __restrict__ deg_dinv)
{
    int i = blockIdx.x * blockDim.x + threadIdx.x;
    if (i < N_NODES) {
        float d = deg_dinv[i];
        deg_dinv[i] = d > 0.f ? rsqrtf(d) : 0.f;
    }
}

// ---------------- exclusive scan of cnt -> off (single block) ----------------
__global__ __launch_bounds__(256) void scan_kernel(
    const int* __restrict__ cnt, int* __restrict__ off)
{
    __shared__ int partial[256];
    __shared__ int base[257];
    const int CH = (N_NODES + 255) / 256;   // 196
    int t = threadIdx.x;
    int lo = t * CH, hi = min(lo + CH, N_NODES);
    int s = 0;
    for (int i = lo; i < hi; ++i) s += cnt[i];
    partial[t] = s;
    __syncthreads();
    if (t == 0) {
        int run = 0;
        for (int i = 0; i < 256; ++i) { base[i] = run; run += partial[i]; }
        base[256] = run;
    }
    __syncthreads();
    int run = base[t];
    for (int i = lo; i < hi; ++i) { off[i] = run; run += cnt[i]; }
    if (t == 0) off[N_NODES] = base[256];
}

// ---------------- scatter edges into CSR-by-destination, fused norm ----------------
__global__ __launch_bounds__(256) void scatter_kernel(
    const int* __restrict__ row, const int* __restrict__ col,
    const float* __restrict__ w, const float* __restrict__ dinv,
    const int* __restrict__ off, int* __restrict__ cur,
    int* __restrict__ src_sorted, float* __restrict__ nrm_sorted)
{
    int i = blockIdx.x * blockDim.x + threadIdx.x;
    int stride = gridDim.x * blockDim.x;
    for (; i < N_EDGES; i += stride) {
        int r = row[i], c = col[i];
        float nr = -dinv[r] * w[i] * dinv[c];
        int pos = off[c] + atomicAdd(&cur[c], 1);
        src_sorted[pos] = r;
        nrm_sorted[pos] = nr;
    }
}

// ---------------- xf = relu(x @ W_in + b_in), written to d_out tail and T0 ----------------
__global__ __launch_bounds__(256) void xf_kernel(
    const float* __restrict__ x, const float* __restrict__ Win,
    const float* __restrict__ bin, float* __restrict__ xf_out,
    float* __restrict__ T0)
{
    __shared__ float Ws[F_IN * EMB];   // 24576 B
    int t = threadIdx.x;
    for (int i = t; i < F_IN * EMB; i += 256) Ws[i] = Win[i];
    __syncthreads();
    int gid = blockIdx.x * 256 + t;
    if (gid >= N_NODES * EMB) return;
    int n = gid / EMB, j = gid - n * EMB;
    const float* xr = x + n * F_IN;
    float acc = bin[j];
#pragma unroll 8
    for (int k = 0; k < F_IN; ++k) acc += xr[k] * Ws[k * EMB + j];
    acc = fmaxf(acc, 0.f);
    xf_out[gid] = acc;
    T0[gid] = acc;
}

// ---------------- out += T @ W (48x48) ----------------
__global__ __launch_bounds__(256) void gemm48_acc_kernel(
    const float* __restrict__ T, const float* __restrict__ W,
    float* __restrict__ out)
{
    __shared__ float Ws[EMB * HID];   // 9216 B
    int t = threadIdx.x;
    for (int i = t; i < EMB * HID; i += 256) Ws[i] = W[i];
    __syncthreads();
    int gid = blockIdx.x * 256 + t;
    if (gid >= N_NODES * HID) return;
    int n = gid / HID, j = gid - n * HID;
    const float* tr = T + n * EMB;
    float acc = 0.f;
#pragma unroll 8
    for (int c = 0; c < EMB; ++c) acc += tr[c] * Ws[c * HID + j];
    out[gid] += acc;
}

// ---------------- tdst = prop(tsrc)  or  tdst = 2*prop(tsrc) - tprev ----------------
// 16 lanes per destination node; lane l owns features {l, l+16, l+32}.
__global__ __launch_bounds__(256) void prop_kernel(
    const int* __restrict__ off, const int* __restrict__ src,
    const float* __restrict__ nrm, const float* __restrict__ tsrc,
    const float* __restrict__ tprev, float* __restrict__ tdst, int cheb_mode)
{
    int gtid = blockIdx.x * 256 + threadIdx.x;
    int g = gtid >> 4;            // destination node
    int lane = gtid & 15;
    if (g >= N_NODES) return;
    int s = off[g], e = off[g + 1];
    float a0 = 0.f, a1 = 0.f, a2 = 0.f;
    for (int p = s; p < e; ++p) {
        int r = src[p];
        float wv = nrm[p];
        const float* tr = tsrc + r * EMB;
        a0 += wv * tr[lane];
        a1 += wv * tr[lane + 16];
        a2 += wv * tr[lane + 32];
    }
    float* td = tdst + g * EMB;
    if (cheb_mode) {
        const float* tp = tprev + g * EMB;
        td[lane]      = 2.f * a0 - tp[lane];
        td[lane + 16] = 2.f * a1 - tp[lane + 16];
        td[lane + 32] = 2.f * a2 - tp[lane + 32];
    } else {
        td[lane]      = a0;
        td[lane + 16] = a1;
        td[lane + 32] = a2;
    }
}

// ---------------- y = relu(out + b_cheb) @ W_out + b_out ----------------
__global__ __launch_bounds__(256) void final_kernel(
    const float* __restrict__ out_acc, const float* __restrict__ bch,
    const float* __restrict__ Wout, const float* __restrict__ bout,
    float* __restrict__ y)
{
    __shared__ float Ws[HID * OUTF];  // 12288 B
    __shared__ float bs[HID];
    int t = threadIdx.x;
    for (int i = t; i < HID * OUTF; i += 256) Ws[i] = Wout[i];
    if (t < HID) bs[t] = bch[t];
    __syncthreads();
    int gid = blockIdx.x * 256 + t;
    if (gid >= N_NODES * OUTF) return;
    int n = gid / OUTF, o = gid - n * OUTF;
    const float* orow = out_acc + n * HID;
    float acc = bout[o];
#pragma unroll 8
    for (int h = 0; h < HID; ++h) {
        float v = fmaxf(orow[h] + bs[h], 0.f);
        acc += v * Ws[h * OUTF + o];
    }
    y[gid] = acc;
}

extern "C" void kernel_launch(void* const* d_in, const int* in_sizes, int n_in,
                              void* d_out, int out_size, void* d_ws, size_t ws_size,
                              hipStream_t stream)
{
    const float* x    = (const float*)d_in[0];
    const int*   ei   = (const int*)d_in[1];
    const float* ew   = (const float*)d_in[2];
    const float* Win  = (const float*)d_in[3];
    const float* bin  = (const float*)d_in[4];
    const float* Wch  = (const float*)d_in[5];   // [7,48,48]
    const float* bch  = (const float*)d_in[6];
    const float* Wout = (const float*)d_in[7];
    const float* bout = (const float*)d_in[8];

    const int* row = ei;
    const int* col = ei + N_EDGES;

    float* y_out  = (float*)d_out;                      // [N,64]
    float* xf_out = (float*)d_out + (size_t)N_NODES * OUTF;  // [N,48]

    // ---- workspace carve (all 256B aligned) ----
    char* p = (char*)d_ws;
    auto carve = [&](size_t bytes) {
        void* q = p;
        p += (bytes + 255) & ~(size_t)255;
        return q;
    };
    // zero region: deg | cnt | cur | out_acc  (one memset)
    char* zero_base = p;
    float* deg     = (float*)carve(N_NODES * 4);
    int*   cnt     = (int*)  carve(N_NODES * 4);
    int*   cur     = (int*)  carve(N_NODES * 4);
    float* out_acc = (float*)carve((size_t)N_NODES * HID * 4);
    size_t zero_bytes = (size_t)(p - zero_base);

    int*   off        = (int*)  carve((N_NODES + 1) * 4);
    int*   src_sorted = (int*)  carve((size_t)N_EDGES * 4);
    float* nrm_sorted = (float*)carve((size_t)N_EDGES * 4);
    float* T0 = (float*)carve((size_t)N_NODES * EMB * 4);
    float* T1 = (float*)carve((size_t)N_NODES * EMB * 4);
    float* T2 = (float*)carve((size_t)N_NODES * EMB * 4);

    hipMemsetAsync(zero_base, 0, zero_bytes, stream);

    // graph preprocessing
    deg_hist_kernel<<<2048, 256, 0, stream>>>(row, col, ew, deg, cnt);
    dinv_kernel<<<(N_NODES + 255) / 256, 256, 0, stream>>>(deg);
    scan_kernel<<<1, 256, 0, stream>>>(cnt, off);
    scatter_kernel<<<2048, 256, 0, stream>>>(row, col, ew, deg, off, cur,
                                             src_sorted, nrm_sorted);

    // xf = relu(x @ W_in + b_in)
    xf_kernel<<<(N_NODES * EMB + 255) / 256, 256, 0, stream>>>(x, Win, bin, xf_out, T0);

    const int gemm_grid = (N_NODES * HID + 255) / 256;
    const int prop_grid = (N_NODES * 16 + 255) / 256;

    // out = T0 @ Wch[0]
    gemm48_acc_kernel<<<gemm_grid, 256, 0, stream>>>(T0, Wch, out_acc);
    // T1 = prop(T0)
    prop_kernel<<<prop_grid, 256, 0, stream>>>(off, src_sorted, nrm_sorted, T0, nullptr, T1, 0);
    gemm48_acc_kernel<<<gemm_grid, 256, 0, stream>>>(T1, Wch + EMB * HID, out_acc);

    float* A = T0; float* B = T1; float* C = T2;
    for (int k = 2; k < KCH; ++k) {
        // C = 2*prop(B) - A
        prop_kernel<<<prop_grid, 256, 0, stream>>>(off, src_sorted, nrm_sorted, B, A, C, 1);
        gemm48_acc_kernel<<<gemm_grid, 256, 0, stream>>>(C, Wch + (size_t)k * EMB * HID, out_acc);
        float* tmp = A; A = B; B = C; C = tmp;
    }

    // y = relu(out + b_cheb) @ W_out + b_out
    final_kernel<<<(N_NODES * OUTF + 255) / 256, 256, 0, stream>>>(out_acc, bch, Wout, bout, y_out);
}

// Round 2
// 808.450 us; speedup vs baseline: 1.1817x; 1.1817x over previous
//
#include <hip/hip_runtime.h>

#define N_NODES 50000
#define N_EDGES 1600000
#define F_IN    128
#define EMB     48
#define HID     48
#define OUTF    64
#define KCH     7

// ---- pass 1: deg[row] += w (float atomic), rank[e] = cnt[col]++ (int atomic) ----
__global__ __launch_bounds__(256) void deg_hist_kernel(
    const int* __restrict__ row, const int* __restrict__ col,
    const float* __restrict__ w, float* __restrict__ deg,
    int* __restrict__ cnt, int* __restrict__ rank)
{
    int i = blockIdx.x * blockDim.x + threadIdx.x;
    int stride = gridDim.x * blockDim.x;
    for (; i < N_EDGES; i += stride) {
        atomicAdd(&deg[row[i]], w[i]);
        rank[i] = atomicAdd(&cnt[col[i]], 1);
    }
}

// ---- dinv = deg>0 ? rsqrt(deg) : 0 (in place) ----
__global__ __launch_bounds__(256) void dinv_kernel(float* __restrict__ deg_dinv)
{
    int i = blockIdx.x * blockDim.x + threadIdx.x;
    if (i < N_NODES) {
        float d = deg_dinv[i];
        deg_dinv[i] = d > 0.f ? rsqrtf(d) : 0.f;
    }
}

// ---- exclusive scan of cnt -> off, single 1024-thread block, shfl-based ----
__global__ __launch_bounds__(1024) void scan_kernel(
    const int* __restrict__ cnt, int* __restrict__ off)
{
    __shared__ int wsum[16];
    const int CH = (N_NODES + 1023) / 1024;   // 49
    int t = threadIdx.x;
    int lo = t * CH, hi = min(lo + CH, N_NODES);
    int s = 0;
    for (int i = lo; i < hi; ++i) s += cnt[i];
    // intra-wave inclusive scan of s
    int lane = t & 63, wid = t >> 6;
    int v = s;
    for (int d = 1; d < 64; d <<= 1) {
        int u = __shfl_up(v, d);
        if (lane >= d) v += u;
    }
    if (lane == 63) wsum[wid] = v;
    __syncthreads();
    if (t == 0) {
        int run = 0;
        for (int i = 0; i < 16; ++i) { int x = wsum[i]; wsum[i] = run; run += x; }
    }
    __syncthreads();
    int run = (v - s) + wsum[wid];   // exclusive prefix for this thread's chunk
    for (int i = lo; i < hi; ++i) { off[i] = run; run += cnt[i]; }
    if (t == 1023) off[N_NODES] = run;  // lo>=N so run == total
}

// ---- scatter edges into CSR-by-destination, atomic-free via rank ----
__global__ __launch_bounds__(256) void scatter_kernel(
    const int* __restrict__ row, const int* __restrict__ col,
    const float* __restrict__ w, const float* __restrict__ dinv,
    const int* __restrict__ off, const int* __restrict__ rank,
    uint2* __restrict__ edges)
{
    int i = blockIdx.x * blockDim.x + threadIdx.x;
    int stride = gridDim.x * blockDim.x;
    for (; i < N_EDGES; i += stride) {
        int r = row[i], c = col[i];
        float nr = -dinv[r] * w[i] * dinv[c];
        int pos = off[c] + rank[i];
        edges[pos] = make_uint2((unsigned)r, __float_as_uint(nr));
    }
}

// ---- xf = relu(x @ W_in + b_in) -> d_out tail (doubles as T0) ----
__global__ __launch_bounds__(256) void xf_kernel(
    const float* __restrict__ x, const float* __restrict__ Win,
    const float* __restrict__ bin, float* __restrict__ xf_out)
{
    __shared__ float Ws[F_IN * EMB];   // 24576 B
    int t = threadIdx.x;
    for (int i = t; i < F_IN * EMB; i += 256) Ws[i] = Win[i];
    __syncthreads();
    int gid = blockIdx.x * 256 + t;
    if (gid >= N_NODES * EMB) return;
    int n = gid / EMB, j = gid - n * EMB;
    const float* xr = x + (size_t)n * F_IN;
    float acc = bin[j];
#pragma unroll 8
    for (int k = 0; k < F_IN; ++k) acc += xr[k] * Ws[k * EMB + j];
    xf_out[gid] = fmaxf(acc, 0.f);
}

// ---- out_acc = T0 @ W0 (write, k=0 term) ----
__global__ __launch_bounds__(256) void gemm48_write_kernel(
    const float* __restrict__ T, const float* __restrict__ W,
    float* __restrict__ out)
{
    __shared__ float Ws[EMB * HID];
    int t = threadIdx.x;
    for (int i = t; i < EMB * HID; i += 256) Ws[i] = W[i];
    __syncthreads();
    int gid = blockIdx.x * 256 + t;
    if (gid >= N_NODES * HID) return;
    int n = gid / HID, j = gid - n * HID;
    const float* tr = T + (size_t)n * EMB;
    float acc = 0.f;
#pragma unroll 8
    for (int c = 0; c < EMB; ++c) acc += tr[c] * Ws[c * HID + j];
    out[gid] = acc;
}

// ---- fused: T_k = prop (or 2*prop - tprev), AND out_acc += T_k @ W_k ----
// block = 256 threads = 16 groups x 16 lanes; 16 dest nodes per block.
__global__ __launch_bounds__(256) void prop_fused_kernel(
    const int* __restrict__ off, const uint2* __restrict__ edges,
    const float* __restrict__ tsrc, const float* __restrict__ tprev,
    float* __restrict__ tdst, const float* __restrict__ Wk,
    float* __restrict__ out_acc, int cheb_mode)
{
    __shared__ float Ws[EMB * HID];     // 9216 B
    __shared__ float tdS[16][EMB + 1];  // pad -> 16 groups hit distinct banks
    int t = threadIdx.x;
    for (int i = t; i < EMB * HID; i += 256) Ws[i] = Wk[i];

    int grp = t >> 4, lane = t & 15;
    int g = blockIdx.x * 16 + grp;      // 50000 % 16 handled by grid exactness

    float a0 = 0.f, a1 = 0.f, a2 = 0.f;
    int s = off[g], e = off[g + 1];
    for (int p = s; p < e; ++p) {
        uint2 er = edges[p];
        float wv = __uint_as_float(er.y);
        const float* tr = tsrc + (size_t)er.x * EMB;
        a0 += wv * tr[lane];
        a1 += wv * tr[lane + 16];
        a2 += wv * tr[lane + 32];
    }
    if (cheb_mode) {
        const float* tp = tprev + (size_t)g * EMB;
        a0 = 2.f * a0 - tp[lane];
        a1 = 2.f * a1 - tp[lane + 16];
        a2 = 2.f * a2 - tp[lane + 32];
    }
    float* td = tdst + (size_t)g * EMB;
    td[lane]      = a0;
    td[lane + 16] = a1;
    td[lane + 32] = a2;
    tdS[grp][lane]      = a0;
    tdS[grp][lane + 16] = a1;
    tdS[grp][lane + 32] = a2;
    __syncthreads();

    // epilogue: out_acc[g] += tdS[grp] @ Ws
    float o0 = 0.f, o1 = 0.f, o2 = 0.f;
#pragma unroll 8
    for (int c = 0; c < EMB; ++c) {
        float tv = tdS[grp][c];                 // broadcast within group
        o0 += tv * Ws[c * HID + lane];
        o1 += tv * Ws[c * HID + lane + 16];
        o2 += tv * Ws[c * HID + lane + 32];
    }
    float* orow = out_acc + (size_t)g * HID;
    orow[lane]      += o0;
    orow[lane + 16] += o1;
    orow[lane + 32] += o2;
}

// ---- y = relu(out_acc + b_cheb) @ W_out + b_out ----
__global__ __launch_bounds__(256) void final_kernel(
    const float* __restrict__ out_acc, const float* __restrict__ bch,
    const float* __restrict__ Wout, const float* __restrict__ bout,
    float* __restrict__ y)
{
    __shared__ float Ws[HID * OUTF];  // 12288 B
    __shared__ float bs[HID];
    int t = threadIdx.x;
    for (int i = t; i < HID * OUTF; i += 256) Ws[i] = Wout[i];
    if (t < HID) bs[t] = bch[t];
    __syncthreads();
    int gid = blockIdx.x * 256 + t;
    if (gid >= N_NODES * OUTF) return;
    int n = gid / OUTF, o = gid - n * OUTF;
    const float* orow = out_acc + (size_t)n * HID;
    float acc = bout[o];
#pragma unroll 8
    for (int h = 0; h < HID; ++h) {
        float v = fmaxf(orow[h] + bs[h], 0.f);
        acc += v * Ws[h * OUTF + o];
    }
    y[gid] = acc;
}

extern "C" void kernel_launch(void* const* d_in, const int* in_sizes, int n_in,
                              void* d_out, int out_size, void* d_ws, size_t ws_size,
                              hipStream_t stream)
{
    const float* x    = (const float*)d_in[0];
    const int*   ei   = (const int*)d_in[1];
    const float* ew   = (const float*)d_in[2];
    const float* Win  = (const float*)d_in[3];
    const float* bin  = (const float*)d_in[4];
    const float* Wch  = (const float*)d_in[5];   // [7,48,48]
    const float* bch  = (const float*)d_in[6];
    const float* Wout = (const float*)d_in[7];
    const float* bout = (const float*)d_in[8];

    const int* row = ei;
    const int* col = ei + N_EDGES;

    float* y_out  = (float*)d_out;                           // [N,64]
    float* xf_out = (float*)d_out + (size_t)N_NODES * OUTF;  // [N,48] == T0

    // ---- workspace carve (256B aligned) ----
    char* p = (char*)d_ws;
    auto carve = [&](size_t bytes) {
        void* q = p;
        p += (bytes + 255) & ~(size_t)255;
        return q;
    };
    char* zero_base = p;
    float* deg = (float*)carve(N_NODES * 4);
    int*   cnt = (int*)  carve(N_NODES * 4);
    size_t zero_bytes = (size_t)(p - zero_base);

    int*   off   = (int*)  carve((N_NODES + 1) * 4);
    int*   rank  = (int*)  carve((size_t)N_EDGES * 4);
    uint2* edges = (uint2*)carve((size_t)N_EDGES * 8);
    float* out_acc = (float*)carve((size_t)N_NODES * HID * 4);
    float* TA = (float*)carve((size_t)N_NODES * EMB * 4);
    float* TB = (float*)carve((size_t)N_NODES * EMB * 4);
    float* TC = (float*)carve((size_t)N_NODES * EMB * 4);

    hipMemsetAsync(zero_base, 0, zero_bytes, stream);

    // graph preprocessing
    deg_hist_kernel<<<2048, 256, 0, stream>>>(row, col, ew, deg, cnt, rank);
    dinv_kernel<<<(N_NODES + 255) / 256, 256, 0, stream>>>(deg);
    scan_kernel<<<1, 1024, 0, stream>>>(cnt, off);
    scatter_kernel<<<2048, 256, 0, stream>>>(row, col, ew, deg, off, rank, edges);

    // xf = relu(x @ W_in + b_in) -> d_out tail (doubles as T0)
    xf_kernel<<<(N_NODES * EMB + 255) / 256, 256, 0, stream>>>(x, Win, bin, xf_out);

    // out_acc = T0 @ W0
    gemm48_write_kernel<<<(N_NODES * HID + 255) / 256, 256, 0, stream>>>(xf_out, Wch, out_acc);

    const int prop_grid = N_NODES / 16;   // 3125, exact

    // T1 = prop(T0); out_acc += T1 @ W1
    prop_fused_kernel<<<prop_grid, 256, 0, stream>>>(off, edges, xf_out, nullptr,
                                                     TA, Wch + EMB * HID, out_acc, 0);
    // Chebyshev recursion with fused GEMM
    const float* A = xf_out;  // T_{k-2}
    float*       B = TA;      // T_{k-1}
    float* bufs[3] = {TB, TC, TA};
    for (int k = 2; k < KCH; ++k) {
        float* C = bufs[(k - 2) % 3];
        prop_fused_kernel<<<prop_grid, 256, 0, stream>>>(off, edges, B, A,
                                                         C, Wch + (size_t)k * EMB * HID, out_acc, 1);
        A = B; B = C;
    }

    // y = relu(out_acc + b_cheb) @ W_out + b_out
    final_kernel<<<(N_NODES * OUTF + 255) / 256, 256, 0, stream>>>(out_acc, bch, Wout, bout, y_out);
}

// Round 4
// 695.364 us; speedup vs baseline: 1.3739x; 1.1626x over previous
//
#include <hip/hip_runtime.h>

#define N_NODES 50000
#define N_EDGES 1600000
#define F_IN    128
#define EMB     48
#define HID     48
#define OUTF    64
#define KCH     7
#define RREP    8          // counter replicas (contention fix)
#define HIST_GRID 2048     // deg_hist and scatter MUST use the same grid

// ---- pass 1: deg_r[rep][row] += w, rank[e] = cnt_r[rep][col]++ ----
__global__ __launch_bounds__(256) void deg_hist_kernel(
    const int* __restrict__ row, const int* __restrict__ col,
    const float* __restrict__ w, float* __restrict__ deg_r,
    int* __restrict__ cnt_r, int* __restrict__ rank)
{
    int rep = blockIdx.x & (RREP - 1);
    float* dr = deg_r + (size_t)rep * N_NODES;
    int*   cr = cnt_r + (size_t)rep * N_NODES;
    int i = blockIdx.x * blockDim.x + threadIdx.x;
    int stride = gridDim.x * blockDim.x;
    for (; i < N_EDGES; i += stride) {
        rank[i] = atomicAdd(&cr[col[i]], 1);
        atomicAdd(&dr[row[i]], w[i]);
    }
}

// ---- fold replicas: dinv, cnt totals, per-replica exclusive prefix (in place) ----
__global__ __launch_bounds__(256) void reduce_kernel(
    float* __restrict__ deg_r, int* __restrict__ cnt_r,
    float* __restrict__ dinv, int* __restrict__ cnt)
{
    int n = blockIdx.x * blockDim.x + threadIdx.x;
    if (n >= N_NODES) return;
    float d = 0.f;
    int c = 0;
    int pre[RREP];
#pragma unroll
    for (int r = 0; r < RREP; ++r) {
        pre[r] = c;
        c += cnt_r[(size_t)r * N_NODES + n];
        d += deg_r[(size_t)r * N_NODES + n];
    }
#pragma unroll
    for (int r = 0; r < RREP; ++r)
        cnt_r[(size_t)r * N_NODES + n] = pre[r];
    cnt[n] = c;
    dinv[n] = d > 0.f ? rsqrtf(d) : 0.f;
}

// ---- exclusive scan of cnt -> off, single 1024-thread block ----
__global__ __launch_bounds__(1024) void scan_kernel(
    const int* __restrict__ cnt, int* __restrict__ off)
{
    __shared__ int wsum[16];
    const int CH = (N_NODES + 1023) / 1024;   // 49
    int t = threadIdx.x;
    int lo = t * CH, hi = min(lo + CH, N_NODES);
    int s = 0;
    for (int i = lo; i < hi; ++i) s += cnt[i];
    int lane = t & 63, wid = t >> 6;
    int v = s;
    for (int d = 1; d < 64; d <<= 1) {
        int u = __shfl_up(v, d);
        if (lane >= d) v += u;
    }
    if (lane == 63) wsum[wid] = v;
    __syncthreads();
    if (t == 0) {
        int run = 0;
        for (int i = 0; i < 16; ++i) { int x = wsum[i]; wsum[i] = run; run += x; }
    }
    __syncthreads();
    int run = (v - s) + wsum[wid];
    for (int i = lo; i < hi; ++i) { off[i] = run; run += cnt[i]; }
    if (t == 1023) off[N_NODES] = run;
}

// ---- scatter edges into CSR-by-destination, atomic-free ----
__global__ __launch_bounds__(256) void scatter_kernel(
    const int* __restrict__ row, const int* __restrict__ col,
    const float* __restrict__ w, const float* __restrict__ dinv,
    const int* __restrict__ off, const int* __restrict__ cnt_pre,
    const int* __restrict__ rank, uint2* __restrict__ edges)
{
    int rep = blockIdx.x & (RREP - 1);   // identical mapping to deg_hist_kernel
    const int* cp = cnt_pre + (size_t)rep * N_NODES;
    int i = blockIdx.x * blockDim.x + threadIdx.x;
    int stride = gridDim.x * blockDim.x;
    for (; i < N_EDGES; i += stride) {
        int r = row[i], c = col[i];
        float nr = -dinv[r] * w[i] * dinv[c];
        int pos = off[c] + cp[c] + rank[i];
        edges[pos] = make_uint2((unsigned)r, __float_as_uint(nr));
    }
}

// ---- xf = relu(x @ W_in + b_in) -> d_out tail (doubles as T0) ----
__global__ __launch_bounds__(256) void xf_kernel(
    const float* __restrict__ x, const float* __restrict__ Win,
    const float* __restrict__ bin, float* __restrict__ xf_out)
{
    __shared__ float Ws[F_IN * EMB];   // 24576 B
    int t = threadIdx.x;
    for (int i = t; i < F_IN * EMB; i += 256) Ws[i] = Win[i];
    __syncthreads();
    int gid = blockIdx.x * 256 + t;
    if (gid >= N_NODES * EMB) return;
    int n = gid / EMB, j = gid - n * EMB;
    const float* xr = x + (size_t)n * F_IN;
    float acc = bin[j];
#pragma unroll 8
    for (int k = 0; k < F_IN; ++k) acc += xr[k] * Ws[k * EMB + j];
    xf_out[gid] = fmaxf(acc, 0.f);
}

// ---- out_acc = T0 @ W0 (write, k=0 term) ----
__global__ __launch_bounds__(256) void gemm48_write_kernel(
    const float* __restrict__ T, const float* __restrict__ W,
    float* __restrict__ out)
{
    __shared__ float Ws[EMB * HID];
    int t = threadIdx.x;
    for (int i = t; i < EMB * HID; i += 256) Ws[i] = W[i];
    __syncthreads();
    int gid = blockIdx.x * 256 + t;
    if (gid >= N_NODES * HID) return;
    int n = gid / HID, j = gid - n * HID;
    const float* tr = T + (size_t)n * EMB;
    float acc = 0.f;
#pragma unroll 8
    for (int c = 0; c < EMB; ++c) acc += tr[c] * Ws[c * HID + j];
    out[gid] = acc;
}

// ---- fused: T_k = prop (or 2*prop - tprev), AND out_acc += T_k @ W_k ----
// 256 threads = 16 groups x 16 lanes; 16 dest nodes per block. Edge loop
// unrolled x4 -> 12 independent gather loads outstanding.
__global__ __launch_bounds__(256) void prop_fused_kernel(
    const int* __restrict__ off, const uint2* __restrict__ edges,
    const float* __restrict__ tsrc, const float* __restrict__ tprev,
    float* __restrict__ tdst, const float* __restrict__ Wk,
    float* __restrict__ out_acc, int cheb_mode)
{
    __shared__ float Ws[EMB * HID];     // 9216 B
    __shared__ float tdS[16][EMB + 1];
    int t = threadIdx.x;
    for (int i = t; i < EMB * HID; i += 256) Ws[i] = Wk[i];

    int grp = t >> 4, lane = t & 15;
    int g = blockIdx.x * 16 + grp;

    float a0 = 0.f, a1 = 0.f, a2 = 0.f;
    int s = off[g], e = off[g + 1];
    int p = s;
    int e4 = s + ((e - s) & ~3);
    for (; p < e4; p += 4) {
        uint2 er0 = edges[p],     er1 = edges[p + 1];
        uint2 er2 = edges[p + 2], er3 = edges[p + 3];
        const float* t0 = tsrc + (size_t)er0.x * EMB;
        const float* t1 = tsrc + (size_t)er1.x * EMB;
        const float* t2 = tsrc + (size_t)er2.x * EMB;
        const float* t3 = tsrc + (size_t)er3.x * EMB;
        float w0 = __uint_as_float(er0.y), w1 = __uint_as_float(er1.y);
        float w2 = __uint_as_float(er2.y), w3 = __uint_as_float(er3.y);
        float v00 = t0[lane], v01 = t0[lane + 16], v02 = t0[lane + 32];
        float v10 = t1[lane], v11 = t1[lane + 16], v12 = t1[lane + 32];
        float v20 = t2[lane], v21 = t2[lane + 16], v22 = t2[lane + 32];
        float v30 = t3[lane], v31 = t3[lane + 16], v32 = t3[lane + 32];
        a0 += w0 * v00; a1 += w0 * v01; a2 += w0 * v02;
        a0 += w1 * v10; a1 += w1 * v11; a2 += w1 * v12;
        a0 += w2 * v20; a1 += w2 * v21; a2 += w2 * v22;
        a0 += w3 * v30; a1 += w3 * v31; a2 += w3 * v32;
    }
    for (; p < e; ++p) {
        uint2 er = edges[p];
        float wv = __uint_as_float(er.y);
        const float* tr = tsrc + (size_t)er.x * EMB;
        a0 += wv * tr[lane];
        a1 += wv * tr[lane + 16];
        a2 += wv * tr[lane + 32];
    }
    if (cheb_mode) {
        const float* tp = tprev + (size_t)g * EMB;
        a0 = 2.f * a0 - tp[lane];
        a1 = 2.f * a1 - tp[lane + 16];
        a2 = 2.f * a2 - tp[lane + 32];
    }
    float* td = tdst + (size_t)g * EMB;
    td[lane]      = a0;
    td[lane + 16] = a1;
    td[lane + 32] = a2;
    tdS[grp][lane]      = a0;
    tdS[grp][lane + 16] = a1;
    tdS[grp][lane + 32] = a2;
    __syncthreads();

    float o0 = 0.f, o1 = 0.f, o2 = 0.f;
#pragma unroll 8
    for (int c = 0; c < EMB; ++c) {
        float tv = tdS[grp][c];
        o0 += tv * Ws[c * HID + lane];
        o1 += tv * Ws[c * HID + lane + 16];
        o2 += tv * Ws[c * HID + lane + 32];
    }
    float* orow = out_acc + (size_t)g * HID;
    orow[lane]      += o0;
    orow[lane + 16] += o1;
    orow[lane + 32] += o2;
}

// ---- y = relu(out_acc + b_cheb) @ W_out + b_out ----
__global__ __launch_bounds__(256) void final_kernel(
    const float* __restrict__ out_acc, const float* __restrict__ bch,
    const float* __restrict__ Wout, const float* __restrict__ bout,
    float* __restrict__ y)
{
    __shared__ float Ws[HID * OUTF];
    __shared__ float bs[HID];
    int t = threadIdx.x;
    for (int i = t; i < HID * OUTF; i += 256) Ws[i] = Wout[i];
    if (t < HID) bs[t] = bch[t];
    __syncthreads();
    int gid = blockIdx.x * 256 + t;
    if (gid >= N_NODES * OUTF) return;
    int n = gid / OUTF, o = gid - n * OUTF;
    const float* orow = out_acc + (size_t)n * HID;
    float acc = bout[o];
#pragma unroll 8
    for (int h = 0; h < HID; ++h) {
        float v = fmaxf(orow[h] + bs[h], 0.f);
        acc += v * Ws[h * OUTF + o];
    }
    y[gid] = acc;
}

extern "C" void kernel_launch(void* const* d_in, const int* in_sizes, int n_in,
                              void* d_out, int out_size, void* d_ws, size_t ws_size,
                              hipStream_t stream)
{
    const float* x    = (const float*)d_in[0];
    const int*   ei   = (const int*)d_in[1];
    const float* ew   = (const float*)d_in[2];
    const float* Win  = (const float*)d_in[3];
    const float* bin  = (const float*)d_in[4];
    const float* Wch  = (const float*)d_in[5];   // [7,48,48]
    const float* bch  = (const float*)d_in[6];
    const float* Wout = (const float*)d_in[7];
    const float* bout = (const float*)d_in[8];

    const int* row = ei;
    const int* col = ei + N_EDGES;

    float* y_out  = (float*)d_out;                           // [N,64]
    float* xf_out = (float*)d_out + (size_t)N_NODES * OUTF;  // [N,48] == T0

    // ---- workspace carve (256B aligned) ----
    char* p = (char*)d_ws;
    auto carve = [&](size_t bytes) {
        void* q = p;
        p += (bytes + 255) & ~(size_t)255;
        return q;
    };
    char* zero_base = p;
    float* deg_r = (float*)carve((size_t)RREP * N_NODES * 4);
    int*   cnt_r = (int*)  carve((size_t)RREP * N_NODES * 4);
    size_t zero_bytes = (size_t)(p - zero_base);

    float* dinv  = (float*)carve(N_NODES * 4);
    int*   cnt   = (int*)  carve(N_NODES * 4);
    int*   off   = (int*)  carve((N_NODES + 1) * 4);
    int*   rank  = (int*)  carve((size_t)N_EDGES * 4);
    uint2* edges = (uint2*)carve((size_t)N_EDGES * 8);
    float* out_acc = (float*)carve((size_t)N_NODES * HID * 4);
    float* TA = (float*)carve((size_t)N_NODES * EMB * 4);
    float* TB = (float*)carve((size_t)N_NODES * EMB * 4);
    float* TC = (float*)carve((size_t)N_NODES * EMB * 4);

    hipMemsetAsync(zero_base, 0, zero_bytes, stream);

    // graph preprocessing
    deg_hist_kernel<<<HIST_GRID, 256, 0, stream>>>(row, col, ew, deg_r, cnt_r, rank);
    reduce_kernel<<<(N_NODES + 255) / 256, 256, 0, stream>>>(deg_r, cnt_r, dinv, cnt);
    scan_kernel<<<1, 1024, 0, stream>>>(cnt, off);
    scatter_kernel<<<HIST_GRID, 256, 0, stream>>>(row, col, ew, dinv, off, cnt_r, rank, edges);

    // xf = relu(x @ W_in + b_in) -> d_out tail (doubles as T0)
    xf_kernel<<<(N_NODES * EMB + 255) / 256, 256, 0, stream>>>(x, Win, bin, xf_out);

    // out_acc = T0 @ W0
    gemm48_write_kernel<<<(N_NODES * HID + 255) / 256, 256, 0, stream>>>(xf_out, Wch, out_acc);

    const int prop_grid = N_NODES / 16;   // 3125, exact

    // T1 = prop(T0); out_acc += T1 @ W1
    prop_fused_kernel<<<prop_grid, 256, 0, stream>>>(off, edges, xf_out, nullptr,
                                                     TA, Wch + EMB * HID, out_acc, 0);
    // Chebyshev recursion with fused GEMM — proven 3-buffer rotation:
    // dst is always a buffer that is neither current src nor needed later.
    const float* A = xf_out;  // T_{k-2}
    float*       B = TA;      // T_{k-1}
    float* bufs[3] = {TB, TC, TA};
    for (int k = 2; k < KCH; ++k) {
        float* C = bufs[(k - 2) % 3];
        prop_fused_kernel<<<prop_grid, 256, 0, stream>>>(off, edges, B, A,
                                                         C, Wch + (size_t)k * EMB * HID, out_acc, 1);
        A = B; B = C;
    }

    // y = relu(out_acc + b_cheb) @ W_out + b_out
    final_kernel<<<(N_NODES * OUTF + 255) / 256, 256, 0, stream>>>(out_acc, bch, Wout, bout, y_out);
}

// Round 5
// 611.111 us; speedup vs baseline: 1.5633x; 1.1379x over previous
//
#include <hip/hip_runtime.h>
#include <hip/hip_fp16.h>

#define N_NODES 50000
#define N_EDGES 1600000
#define F_IN    128
#define EMB     48
#define HID     48
#define OUTF    64
#define KCH     7
#define RREP    8          // counter replicas
#define HIST_GRID 2048     // deg_hist and scatter MUST use the same grid

// ---- pass 1: deg_r[rep][row] += w, rank[e] = cnt_r[rep][col]++ ----
__global__ __launch_bounds__(256) void deg_hist_kernel(
    const int* __restrict__ row, const int* __restrict__ col,
    const float* __restrict__ w, float* __restrict__ deg_r,
    int* __restrict__ cnt_r, int* __restrict__ rank)
{
    int rep = blockIdx.x & (RREP - 1);
    float* dr = deg_r + (size_t)rep * N_NODES;
    int*   cr = cnt_r + (size_t)rep * N_NODES;
    int i = blockIdx.x * blockDim.x + threadIdx.x;
    int stride = gridDim.x * blockDim.x;
    for (; i < N_EDGES; i += stride) {
        rank[i] = atomicAdd(&cr[col[i]], 1);
        atomicAdd(&dr[row[i]], w[i]);
    }
}

// ---- fold replicas: dinv, cnt totals, per-replica exclusive prefix (in place) ----
__global__ __launch_bounds__(256) void reduce_kernel(
    float* __restrict__ deg_r, int* __restrict__ cnt_r,
    float* __restrict__ dinv, int* __restrict__ cnt)
{
    int n = blockIdx.x * blockDim.x + threadIdx.x;
    if (n >= N_NODES) return;
    float d = 0.f;
    int c = 0;
    int pre[RREP];
#pragma unroll
    for (int r = 0; r < RREP; ++r) {
        pre[r] = c;
        c += cnt_r[(size_t)r * N_NODES + n];
        d += deg_r[(size_t)r * N_NODES + n];
    }
#pragma unroll
    for (int r = 0; r < RREP; ++r)
        cnt_r[(size_t)r * N_NODES + n] = pre[r];
    cnt[n] = c;
    dinv[n] = d > 0.f ? rsqrtf(d) : 0.f;
}

// ---- exclusive scan of cnt -> off, single 1024-thread block ----
__global__ __launch_bounds__(1024) void scan_kernel(
    const int* __restrict__ cnt, int* __restrict__ off)
{
    __shared__ int wsum[16];
    const int CH = (N_NODES + 1023) / 1024;   // 49
    int t = threadIdx.x;
    int lo = t * CH, hi = min(lo + CH, N_NODES);
    int s = 0;
    for (int i = lo; i < hi; ++i) s += cnt[i];
    int lane = t & 63, wid = t >> 6;
    int v = s;
    for (int d = 1; d < 64; d <<= 1) {
        int u = __shfl_up(v, d);
        if (lane >= d) v += u;
    }
    if (lane == 63) wsum[wid] = v;
    __syncthreads();
    if (t == 0) {
        int run = 0;
        for (int i = 0; i < 16; ++i) { int x = wsum[i]; wsum[i] = run; run += x; }
    }
    __syncthreads();
    int run = (v - s) + wsum[wid];
    for (int i = lo; i < hi; ++i) { off[i] = run; run += cnt[i]; }
    if (t == 1023) off[N_NODES] = run;
}

// ---- scatter edges into CSR-by-destination, atomic-free ----
__global__ __launch_bounds__(256) void scatter_kernel(
    const int* __restrict__ row, const int* __restrict__ col,
    const float* __restrict__ w, const float* __restrict__ dinv,
    const int* __restrict__ off, const int* __restrict__ cnt_pre,
    const int* __restrict__ rank, uint2* __restrict__ edges)
{
    int rep = blockIdx.x & (RREP - 1);   // identical mapping to deg_hist_kernel
    const int* cp = cnt_pre + (size_t)rep * N_NODES;
    int i = blockIdx.x * blockDim.x + threadIdx.x;
    int stride = gridDim.x * blockDim.x;
    for (; i < N_EDGES; i += stride) {
        int r = row[i], c = col[i];
        float nr = -dinv[r] * w[i] * dinv[c];
        int pos = off[c] + cp[c] + rank[i];
        edges[pos] = make_uint2((unsigned)r, __float_as_uint(nr));
    }
}

// ---- xf = relu(x @ W_in + b_in) -> f32 d_out tail AND fp16 T0 ----
__global__ __launch_bounds__(256) void xf_kernel(
    const float* __restrict__ x, const float* __restrict__ Win,
    const float* __restrict__ bin, float* __restrict__ xf_out,
    __half* __restrict__ T0h)
{
    __shared__ float Ws[F_IN * EMB];   // 24576 B
    int t = threadIdx.x;
    for (int i = t; i < F_IN * EMB; i += 256) Ws[i] = Win[i];
    __syncthreads();
    int gid = blockIdx.x * 256 + t;
    if (gid >= N_NODES * EMB) return;
    int n = gid / EMB, j = gid - n * EMB;
    const float* xr = x + (size_t)n * F_IN;
    float acc = bin[j];
#pragma unroll 8
    for (int k = 0; k < F_IN; ++k) acc += xr[k] * Ws[k * EMB + j];
    acc = fmaxf(acc, 0.f);
    xf_out[gid] = acc;
    T0h[gid] = __float2half_rn(acc);
}

// ---- out_acc = T0 @ W0 (write, k=0 term; reads exact f32 xf) ----
__global__ __launch_bounds__(256) void gemm48_write_kernel(
    const float* __restrict__ T, const float* __restrict__ W,
    float* __restrict__ out)
{
    __shared__ float Ws[EMB * HID];
    int t = threadIdx.x;
    for (int i = t; i < EMB * HID; i += 256) Ws[i] = W[i];
    __syncthreads();
    int gid = blockIdx.x * 256 + t;
    if (gid >= N_NODES * HID) return;
    int n = gid / HID, j = gid - n * HID;
    const float* tr = T + (size_t)n * EMB;
    float acc = 0.f;
#pragma unroll 8
    for (int c = 0; c < EMB; ++c) acc += tr[c] * Ws[c * HID + j];
    out[gid] = acc;
}

// ---- fused: T_k = prop (or 2*prop - tprev) in fp16, out_acc += T_k @ W_k ----
// 256 threads = 16 groups x 16 lanes; 16 dest nodes per block. Gathers are
// fp16 (96 B/row, 3 coalesced 32B chunks per group); accumulate f32; epilogue
// GEMM uses unrounded f32; T stored rounded fp16. Edge loop unrolled x4.
__global__ __launch_bounds__(256) void prop_fused_kernel(
    const int* __restrict__ off, const uint2* __restrict__ edges,
    const __half* __restrict__ tsrc, const __half* __restrict__ tprev,
    __half* __restrict__ tdst, const float* __restrict__ Wk,
    float* __restrict__ out_acc, int cheb_mode)
{
    __shared__ float Ws[EMB * HID];     // 9216 B
    __shared__ float tdS[16][EMB + 1];
    int t = threadIdx.x;
    for (int i = t; i < EMB * HID; i += 256) Ws[i] = Wk[i];

    int grp = t >> 4, lane = t & 15;
    int g = blockIdx.x * 16 + grp;

    float a0 = 0.f, a1 = 0.f, a2 = 0.f;
    int s = off[g], e = off[g + 1];
    int p = s;
    int e4 = s + ((e - s) & ~3);
    for (; p < e4; p += 4) {
        uint2 er0 = edges[p],     er1 = edges[p + 1];
        uint2 er2 = edges[p + 2], er3 = edges[p + 3];
        const __half* t0 = tsrc + (size_t)er0.x * EMB;
        const __half* t1 = tsrc + (size_t)er1.x * EMB;
        const __half* t2 = tsrc + (size_t)er2.x * EMB;
        const __half* t3 = tsrc + (size_t)er3.x * EMB;
        float w0 = __uint_as_float(er0.y), w1 = __uint_as_float(er1.y);
        float w2 = __uint_as_float(er2.y), w3 = __uint_as_float(er3.y);
        float v00 = __half2float(t0[lane]);
        float v01 = __half2float(t0[lane + 16]);
        float v02 = __half2float(t0[lane + 32]);
        float v10 = __half2float(t1[lane]);
        float v11 = __half2float(t1[lane + 16]);
        float v12 = __half2float(t1[lane + 32]);
        float v20 = __half2float(t2[lane]);
        float v21 = __half2float(t2[lane + 16]);
        float v22 = __half2float(t2[lane + 32]);
        float v30 = __half2float(t3[lane]);
        float v31 = __half2float(t3[lane + 16]);
        float v32 = __half2float(t3[lane + 32]);
        a0 += w0 * v00; a1 += w0 * v01; a2 += w0 * v02;
        a0 += w1 * v10; a1 += w1 * v11; a2 += w1 * v12;
        a0 += w2 * v20; a1 += w2 * v21; a2 += w2 * v22;
        a0 += w3 * v30; a1 += w3 * v31; a2 += w3 * v32;
    }
    for (; p < e; ++p) {
        uint2 er = edges[p];
        float wv = __uint_as_float(er.y);
        const __half* tr = tsrc + (size_t)er.x * EMB;
        a0 += wv * __half2float(tr[lane]);
        a1 += wv * __half2float(tr[lane + 16]);
        a2 += wv * __half2float(tr[lane + 32]);
    }
    if (cheb_mode) {
        const __half* tp = tprev + (size_t)g * EMB;
        a0 = 2.f * a0 - __half2float(tp[lane]);
        a1 = 2.f * a1 - __half2float(tp[lane + 16]);
        a2 = 2.f * a2 - __half2float(tp[lane + 32]);
    }
    __half* td = tdst + (size_t)g * EMB;
    td[lane]      = __float2half_rn(a0);
    td[lane + 16] = __float2half_rn(a1);
    td[lane + 32] = __float2half_rn(a2);
    tdS[grp][lane]      = a0;
    tdS[grp][lane + 16] = a1;
    tdS[grp][lane + 32] = a2;
    __syncthreads();

    float o0 = 0.f, o1 = 0.f, o2 = 0.f;
#pragma unroll 8
    for (int c = 0; c < EMB; ++c) {
        float tv = tdS[grp][c];
        o0 += tv * Ws[c * HID + lane];
        o1 += tv * Ws[c * HID + lane + 16];
        o2 += tv * Ws[c * HID + lane + 32];
    }
    float* orow = out_acc + (size_t)g * HID;
    orow[lane]      += o0;
    orow[lane + 16] += o1;
    orow[lane + 32] += o2;
}

// ---- y = relu(out_acc + b_cheb) @ W_out + b_out ----
__global__ __launch_bounds__(256) void final_kernel(
    const float* __restrict__ out_acc, const float* __restrict__ bch,
    const float* __restrict__ Wout, const float* __restrict__ bout,
    float* __restrict__ y)
{
    __shared__ float Ws[HID * OUTF];
    __shared__ float bs[HID];
    int t = threadIdx.x;
    for (int i = t; i < HID * OUTF; i += 256) Ws[i] = Wout[i];
    if (t < HID) bs[t] = bch[t];
    __syncthreads();
    int gid = blockIdx.x * 256 + t;
    if (gid >= N_NODES * OUTF) return;
    int n = gid / OUTF, o = gid - n * OUTF;
    const float* orow = out_acc + (size_t)n * HID;
    float acc = bout[o];
#pragma unroll 8
    for (int h = 0; h < HID; ++h) {
        float v = fmaxf(orow[h] + bs[h], 0.f);
        acc += v * Ws[h * OUTF + o];
    }
    y[gid] = acc;
}

extern "C" void kernel_launch(void* const* d_in, const int* in_sizes, int n_in,
                              void* d_out, int out_size, void* d_ws, size_t ws_size,
                              hipStream_t stream)
{
    const float* x    = (const float*)d_in[0];
    const int*   ei   = (const int*)d_in[1];
    const float* ew   = (const float*)d_in[2];
    const float* Win  = (const float*)d_in[3];
    const float* bin  = (const float*)d_in[4];
    const float* Wch  = (const float*)d_in[5];   // [7,48,48]
    const float* bch  = (const float*)d_in[6];
    const float* Wout = (const float*)d_in[7];
    const float* bout = (const float*)d_in[8];

    const int* row = ei;
    const int* col = ei + N_EDGES;

    float* y_out  = (float*)d_out;                           // [N,64]
    float* xf_out = (float*)d_out + (size_t)N_NODES * OUTF;  // [N,48]

    // ---- workspace carve (256B aligned) ----
    char* p = (char*)d_ws;
    auto carve = [&](size_t bytes) {
        void* q = p;
        p += (bytes + 255) & ~(size_t)255;
        return q;
    };
    char* zero_base = p;
    float* deg_r = (float*)carve((size_t)RREP * N_NODES * 4);
    int*   cnt_r = (int*)  carve((size_t)RREP * N_NODES * 4);
    size_t zero_bytes = (size_t)(p - zero_base);

    float* dinv  = (float*)carve(N_NODES * 4);
    int*   cnt   = (int*)  carve(N_NODES * 4);
    int*   off   = (int*)  carve((N_NODES + 1) * 4);
    int*   rank  = (int*)  carve((size_t)N_EDGES * 4);
    uint2* edges = (uint2*)carve((size_t)N_EDGES * 8);
    float* out_acc = (float*)carve((size_t)N_NODES * HID * 4);
    __half* T0h = (__half*)carve((size_t)N_NODES * EMB * 2);
    __half* TAh = (__half*)carve((size_t)N_NODES * EMB * 2);
    __half* TBh = (__half*)carve((size_t)N_NODES * EMB * 2);
    __half* TCh = (__half*)carve((size_t)N_NODES * EMB * 2);

    hipMemsetAsync(zero_base, 0, zero_bytes, stream);

    // graph preprocessing
    deg_hist_kernel<<<HIST_GRID, 256, 0, stream>>>(row, col, ew, deg_r, cnt_r, rank);
    reduce_kernel<<<(N_NODES + 255) / 256, 256, 0, stream>>>(deg_r, cnt_r, dinv, cnt);
    scan_kernel<<<1, 1024, 0, stream>>>(cnt, off);
    scatter_kernel<<<HIST_GRID, 256, 0, stream>>>(row, col, ew, dinv, off, cnt_r, rank, edges);

    // xf = relu(x @ W_in + b_in) -> f32 d_out tail + fp16 T0
    xf_kernel<<<(N_NODES * EMB + 255) / 256, 256, 0, stream>>>(x, Win, bin, xf_out, T0h);

    // out_acc = T0 @ W0 (exact f32)
    gemm48_write_kernel<<<(N_NODES * HID + 255) / 256, 256, 0, stream>>>(xf_out, Wch, out_acc);

    const int prop_grid = N_NODES / 16;   // 3125, exact

    // T1 = prop(T0); out_acc += T1 @ W1
    prop_fused_kernel<<<prop_grid, 256, 0, stream>>>(off, edges, T0h, nullptr,
                                                     TAh, Wch + EMB * HID, out_acc, 0);
    // Chebyshev recursion with fused GEMM — proven 3-buffer rotation.
    const __half* A = T0h;  // T_{k-2}
    __half*       B = TAh;  // T_{k-1}
    __half* bufs[3] = {TBh, TCh, TAh};
    for (int k = 2; k < KCH; ++k) {
        __half* C = bufs[(k - 2) % 3];
        prop_fused_kernel<<<prop_grid, 256, 0, stream>>>(off, edges, B, A,
                                                         C, Wch + (size_t)k * EMB * HID, out_acc, 1);
        A = B; B = C;
    }

    // y = relu(out_acc + b_cheb) @ W_out + b_out
    final_kernel<<<(N_NODES * OUTF + 255) / 256, 256, 0, stream>>>(out_acc, bch, Wout, bout, y_out);
}

// Round 6
// 575.756 us; speedup vs baseline: 1.6593x; 1.0614x over previous
//
#include <hip/hip_runtime.h>
#include <hip/hip_fp16.h>

#define N_NODES 50000
#define N_EDGES 1600000
#define F_IN    128
#define EMB     48
#define HID     48
#define OUTF    64
#define KCH     7

#define NR    8                      // node ranges (LDS partitions)
#define RANGE (N_NODES / NR)         // 6250 counters = 25 KB LDS
#define BPR   64                     // edge slices
#define SLICE (N_EDGES / BPR)        // 25000 edges per slice

// ---- pass A: partitioned LDS histogram (cnt by col, deg by row), no atomics ----
__global__ __launch_bounds__(256) void hist_part_kernel(
    const int* __restrict__ row, const int* __restrict__ col,
    const float* __restrict__ w,
    unsigned* __restrict__ pc, float* __restrict__ pd)
{
    __shared__ unsigned lc[RANGE];   // 25000 B
    __shared__ float    ld[RANGE];   // 25000 B
    int t = threadIdx.x;
    for (int i = t; i < RANGE; i += 256) { lc[i] = 0u; ld[i] = 0.f; }
    __syncthreads();
    int r = blockIdx.x / BPR;        // node range
    int b = blockIdx.x % BPR;        // edge slice
    int base = r * RANGE;
    int lo = b * SLICE;
    for (int e = lo + t; e < lo + SLICE; e += 256) {
        int c = col[e] - base;
        if ((unsigned)c < RANGE) atomicAdd(&lc[c], 1u);
        int rw = row[e] - base;
        if ((unsigned)rw < RANGE) atomicAdd(&ld[rw], w[e]);
    }
    __syncthreads();
    unsigned* pcb = pc + (size_t)blockIdx.x * RANGE;
    float*    pdb = pd + (size_t)blockIdx.x * RANGE;
    for (int i = t; i < RANGE; i += 256) { pcb[i] = lc[i]; pdb[i] = ld[i]; }
}

// ---- fold partials: dinv, cnt totals, per-slice exclusive prefix (pc in place) ----
__global__ __launch_bounds__(256) void reduce_kernel(
    unsigned* __restrict__ pc, const float* __restrict__ pd,
    float* __restrict__ dinv, int* __restrict__ cnt)
{
    int n = blockIdx.x * 256 + threadIdx.x;
    if (n >= N_NODES) return;
    int r = n / RANGE, i = n - r * RANGE;
    size_t base = (size_t)r * BPR * RANGE + i;
    unsigned csum = 0; float d = 0.f;
    for (int b = 0; b < BPR; ++b) {
        size_t idx = base + (size_t)b * RANGE;
        unsigned x = pc[idx];
        pc[idx] = csum;
        csum += x;
        d += pd[idx];
    }
    cnt[n] = (int)csum;
    dinv[n] = d > 0.f ? rsqrtf(d) : 0.f;
}

// ---- exclusive scan of cnt -> off, single 1024-thread block ----
__global__ __launch_bounds__(1024) void scan_kernel(
    const int* __restrict__ cnt, int* __restrict__ off)
{
    __shared__ int wsum[16];
    const int CH = (N_NODES + 1023) / 1024;   // 49
    int t = threadIdx.x;
    int lo = t * CH, hi = min(lo + CH, N_NODES);
    int s = 0;
    for (int i = lo; i < hi; ++i) s += cnt[i];
    int lane = t & 63, wid = t >> 6;
    int v = s;
    for (int d = 1; d < 64; d <<= 1) {
        int u = __shfl_up(v, d);
        if (lane >= d) v += u;
    }
    if (lane == 63) wsum[wid] = v;
    __syncthreads();
    if (t == 0) {
        int run = 0;
        for (int i = 0; i < 16; ++i) { int x = wsum[i]; wsum[i] = run; run += x; }
    }
    __syncthreads();
    int run = (v - s) + wsum[wid];
    for (int i = lo; i < hi; ++i) { off[i] = run; run += cnt[i]; }
    if (t == 1023) off[N_NODES] = run;
}

// ---- pass D: scatter via re-derived LDS ranks — zero global atomics ----
__global__ __launch_bounds__(256) void scatter_part_kernel(
    const int* __restrict__ row, const int* __restrict__ col,
    const float* __restrict__ w, const float* __restrict__ dinv,
    const int* __restrict__ off, const unsigned* __restrict__ pc,
    uint2* __restrict__ edges)
{
    __shared__ unsigned lc[RANGE];   // 25000 B
    int t = threadIdx.x;
    for (int i = t; i < RANGE; i += 256) lc[i] = 0u;
    __syncthreads();
    int r = blockIdx.x / BPR;
    int b = blockIdx.x % BPR;
    int base = r * RANGE;
    int lo = b * SLICE;
    const unsigned* pcb = pc + (size_t)blockIdx.x * RANGE;
    for (int e = lo + t; e < lo + SLICE; e += 256) {
        int c = col[e];
        int ci = c - base;
        int rw = row[e];
        float we = w[e];
        if ((unsigned)ci < RANGE) {
            unsigned lrank = atomicAdd(&lc[ci], 1u);
            float nr = -dinv[rw] * we * dinv[c];
            int pos = off[c] + (int)pcb[ci] + (int)lrank;
            edges[pos] = make_uint2((unsigned)rw, __float_as_uint(nr));
        }
    }
}

// ---- xf = relu(x @ W_in + b_in) -> f32 d_out tail AND fp16 T0 ----
__global__ __launch_bounds__(256) void xf_kernel(
    const float* __restrict__ x, const float* __restrict__ Win,
    const float* __restrict__ bin, float* __restrict__ xf_out,
    __half* __restrict__ T0h)
{
    __shared__ float Ws[F_IN * EMB];   // 24576 B
    int t = threadIdx.x;
    for (int i = t; i < F_IN * EMB; i += 256) Ws[i] = Win[i];
    __syncthreads();
    int gid = blockIdx.x * 256 + t;
    if (gid >= N_NODES * EMB) return;
    int n = gid / EMB, j = gid - n * EMB;
    const float* xr = x + (size_t)n * F_IN;
    float acc = bin[j];
#pragma unroll 8
    for (int k = 0; k < F_IN; ++k) acc += xr[k] * Ws[k * EMB + j];
    acc = fmaxf(acc, 0.f);
    xf_out[gid] = acc;
    T0h[gid] = __float2half_rn(acc);
}

// ---- out_acc = T0 @ W0 (write, k=0 term; reads exact f32 xf) ----
__global__ __launch_bounds__(256) void gemm48_write_kernel(
    const float* __restrict__ T, const float* __restrict__ W,
    float* __restrict__ out)
{
    __shared__ float Ws[EMB * HID];
    int t = threadIdx.x;
    for (int i = t; i < EMB * HID; i += 256) Ws[i] = W[i];
    __syncthreads();
    int gid = blockIdx.x * 256 + t;
    if (gid >= N_NODES * HID) return;
    int n = gid / HID, j = gid - n * HID;
    const float* tr = T + (size_t)n * EMB;
    float acc = 0.f;
#pragma unroll 8
    for (int c = 0; c < EMB; ++c) acc += tr[c] * Ws[c * HID + j];
    out[gid] = acc;
}

// ---- fused: T_k = prop (or 2*prop - tprev) in fp16, out_acc += T_k @ W_k ----
__global__ __launch_bounds__(256) void prop_fused_kernel(
    const int* __restrict__ off, const uint2* __restrict__ edges,
    const __half* __restrict__ tsrc, const __half* __restrict__ tprev,
    __half* __restrict__ tdst, const float* __restrict__ Wk,
    float* __restrict__ out_acc, int cheb_mode)
{
    __shared__ float Ws[EMB * HID];     // 9216 B
    __shared__ float tdS[16][EMB + 1];
    int t = threadIdx.x;
    for (int i = t; i < EMB * HID; i += 256) Ws[i] = Wk[i];

    int grp = t >> 4, lane = t & 15;
    int g = blockIdx.x * 16 + grp;

    float a0 = 0.f, a1 = 0.f, a2 = 0.f;
    int s = off[g], e = off[g + 1];
    int p = s;
    int e4 = s + ((e - s) & ~3);
    for (; p < e4; p += 4) {
        uint2 er0 = edges[p],     er1 = edges[p + 1];
        uint2 er2 = edges[p + 2], er3 = edges[p + 3];
        const __half* t0 = tsrc + (size_t)er0.x * EMB;
        const __half* t1 = tsrc + (size_t)er1.x * EMB;
        const __half* t2 = tsrc + (size_t)er2.x * EMB;
        const __half* t3 = tsrc + (size_t)er3.x * EMB;
        float w0 = __uint_as_float(er0.y), w1 = __uint_as_float(er1.y);
        float w2 = __uint_as_float(er2.y), w3 = __uint_as_float(er3.y);
        float v00 = __half2float(t0[lane]);
        float v01 = __half2float(t0[lane + 16]);
        float v02 = __half2float(t0[lane + 32]);
        float v10 = __half2float(t1[lane]);
        float v11 = __half2float(t1[lane + 16]);
        float v12 = __half2float(t1[lane + 32]);
        float v20 = __half2float(t2[lane]);
        float v21 = __half2float(t2[lane + 16]);
        float v22 = __half2float(t2[lane + 32]);
        float v30 = __half2float(t3[lane]);
        float v31 = __half2float(t3[lane + 16]);
        float v32 = __half2float(t3[lane + 32]);
        a0 += w0 * v00; a1 += w0 * v01; a2 += w0 * v02;
        a0 += w1 * v10; a1 += w1 * v11; a2 += w1 * v12;
        a0 += w2 * v20; a1 += w2 * v21; a2 += w2 * v22;
        a0 += w3 * v30; a1 += w3 * v31; a2 += w3 * v32;
    }
    for (; p < e; ++p) {
        uint2 er = edges[p];
        float wv = __uint_as_float(er.y);
        const __half* tr = tsrc + (size_t)er.x * EMB;
        a0 += wv * __half2float(tr[lane]);
        a1 += wv * __half2float(tr[lane + 16]);
        a2 += wv * __half2float(tr[lane + 32]);
    }
    if (cheb_mode) {
        const __half* tp = tprev + (size_t)g * EMB;
        a0 = 2.f * a0 - __half2float(tp[lane]);
        a1 = 2.f * a1 - __half2float(tp[lane + 16]);
        a2 = 2.f * a2 - __half2float(tp[lane + 32]);
    }
    __half* td = tdst + (size_t)g * EMB;
    td[lane]      = __float2half_rn(a0);
    td[lane + 16] = __float2half_rn(a1);
    td[lane + 32] = __float2half_rn(a2);
    tdS[grp][lane]      = a0;
    tdS[grp][lane + 16] = a1;
    tdS[grp][lane + 32] = a2;
    __syncthreads();

    float o0 = 0.f, o1 = 0.f, o2 = 0.f;
#pragma unroll 8
    for (int c = 0; c < EMB; ++c) {
        float tv = tdS[grp][c];
        o0 += tv * Ws[c * HID + lane];
        o1 += tv * Ws[c * HID + lane + 16];
        o2 += tv * Ws[c * HID + lane + 32];
    }
    float* orow = out_acc + (size_t)g * HID;
    orow[lane]      += o0;
    orow[lane + 16] += o1;
    orow[lane + 32] += o2;
}

// ---- y = relu(out_acc + b_cheb) @ W_out + b_out ----
__global__ __launch_bounds__(256) void final_kernel(
    const float* __restrict__ out_acc, const float* __restrict__ bch,
    const float* __restrict__ Wout, const float* __restrict__ bout,
    float* __restrict__ y)
{
    __shared__ float Ws[HID * OUTF];
    __shared__ float bs[HID];
    int t = threadIdx.x;
    for (int i = t; i < HID * OUTF; i += 256) Ws[i] = Wout[i];
    if (t < HID) bs[t] = bch[t];
    __syncthreads();
    int gid = blockIdx.x * 256 + t;
    if (gid >= N_NODES * OUTF) return;
    int n = gid / OUTF, o = gid - n * OUTF;
    const float* orow = out_acc + (size_t)n * HID;
    float acc = bout[o];
#pragma unroll 8
    for (int h = 0; h < HID; ++h) {
        float v = fmaxf(orow[h] + bs[h], 0.f);
        acc += v * Ws[h * OUTF + o];
    }
    y[gid] = acc;
}

extern "C" void kernel_launch(void* const* d_in, const int* in_sizes, int n_in,
                              void* d_out, int out_size, void* d_ws, size_t ws_size,
                              hipStream_t stream)
{
    const float* x    = (const float*)d_in[0];
    const int*   ei   = (const int*)d_in[1];
    const float* ew   = (const float*)d_in[2];
    const float* Win  = (const float*)d_in[3];
    const float* bin  = (const float*)d_in[4];
    const float* Wch  = (const float*)d_in[5];   // [7,48,48]
    const float* bch  = (const float*)d_in[6];
    const float* Wout = (const float*)d_in[7];
    const float* bout = (const float*)d_in[8];

    const int* row = ei;
    const int* col = ei + N_EDGES;

    float* y_out  = (float*)d_out;                           // [N,64]
    float* xf_out = (float*)d_out + (size_t)N_NODES * OUTF;  // [N,48]

    // ---- workspace carve (256B aligned); every buffer fully written before read,
    // so no memset is needed anywhere. ----
    char* p = (char*)d_ws;
    auto carve = [&](size_t bytes) {
        void* q = p;
        p += (bytes + 255) & ~(size_t)255;
        return q;
    };
    unsigned* pc  = (unsigned*)carve((size_t)NR * BPR * RANGE * 4);  // 12.8 MB
    float*    pd  = (float*)   carve((size_t)NR * BPR * RANGE * 4);  // 12.8 MB
    float*    dinv = (float*)carve(N_NODES * 4);
    int*      cnt  = (int*)  carve(N_NODES * 4);
    int*      off  = (int*)  carve((N_NODES + 1) * 4);
    uint2*    edges = (uint2*)carve((size_t)N_EDGES * 8);
    float*    out_acc = (float*)carve((size_t)N_NODES * HID * 4);
    __half*   T0h = (__half*)carve((size_t)N_NODES * EMB * 2);
    __half*   TAh = (__half*)carve((size_t)N_NODES * EMB * 2);
    __half*   TBh = (__half*)carve((size_t)N_NODES * EMB * 2);
    __half*   TCh = (__half*)carve((size_t)N_NODES * EMB * 2);

    // graph preprocessing — zero global atomics
    hist_part_kernel<<<NR * BPR, 256, 0, stream>>>(row, col, ew, pc, pd);
    reduce_kernel<<<(N_NODES + 255) / 256, 256, 0, stream>>>(pc, pd, dinv, cnt);
    scan_kernel<<<1, 1024, 0, stream>>>(cnt, off);
    scatter_part_kernel<<<NR * BPR, 256, 0, stream>>>(row, col, ew, dinv, off, pc, edges);

    // xf = relu(x @ W_in + b_in) -> f32 d_out tail + fp16 T0
    xf_kernel<<<(N_NODES * EMB + 255) / 256, 256, 0, stream>>>(x, Win, bin, xf_out, T0h);

    // out_acc = T0 @ W0 (exact f32)
    gemm48_write_kernel<<<(N_NODES * HID + 255) / 256, 256, 0, stream>>>(xf_out, Wch, out_acc);

    const int prop_grid = N_NODES / 16;   // 3125, exact

    // T1 = prop(T0); out_acc += T1 @ W1
    prop_fused_kernel<<<prop_grid, 256, 0, stream>>>(off, edges, T0h, nullptr,
                                                     TAh, Wch + EMB * HID, out_acc, 0);
    // Chebyshev recursion with fused GEMM — proven 3-buffer rotation.
    const __half* A = T0h;  // T_{k-2}
    __half*       B = TAh;  // T_{k-1}
    __half* bufs[3] = {TBh, TCh, TAh};
    for (int k = 2; k < KCH; ++k) {
        __half* C = bufs[(k - 2) % 3];
        prop_fused_kernel<<<prop_grid, 256, 0, stream>>>(off, edges, B, A,
                                                         C, Wch + (size_t)k * EMB * HID, out_acc, 1);
        A = B; B = C;
    }

    // y = relu(out_acc + b_cheb) @ W_out + b_out
    final_kernel<<<(N_NODES * OUTF + 255) / 256, 256, 0, stream>>>(out_acc, bch, Wout, bout, y_out);
}

// Round 7
// 475.926 us; speedup vs baseline: 2.0074x; 1.2098x over previous
//
#include <hip/hip_runtime.h>
#include <hip/hip_fp16.h>

#define N_NODES 50000
#define N_EDGES 1600000
#define F_IN    128
#define EMB     48
#define HID     48
#define OUTF    64
#define KCH     7

#define NR    8                      // node ranges (LDS partitions)
#define RANGE (N_NODES / NR)         // 6250 counters
#define BPR   64                     // edge slices
#define SLICE (N_EDGES / BPR)        // 25000 edges per slice (div by 4)
#define HTHREADS 512

// ---- pass A: partitioned LDS histogram (cnt by col packed u16, deg by row f32) ----
__global__ __launch_bounds__(HTHREADS) void hist_part_kernel(
    const int* __restrict__ row, const int* __restrict__ col,
    const float* __restrict__ w,
    unsigned short* __restrict__ pc, float* __restrict__ pd)
{
    __shared__ unsigned lc32[RANGE / 2];  // 12.5 KB, 2 u16 counters per word
    __shared__ float    ld[RANGE];        // 25 KB
    int t = threadIdx.x;
    for (int i = t; i < RANGE / 2; i += HTHREADS) lc32[i] = 0u;
    for (int i = t; i < RANGE; i += HTHREADS) ld[i] = 0.f;
    __syncthreads();
    int r = blockIdx.x / BPR;        // node range
    int b = blockIdx.x % BPR;        // edge slice
    int base = r * RANGE;
    int lo = b * SLICE;
    for (int e0 = lo + t * 4; e0 < lo + SLICE; e0 += HTHREADS * 4) {
        int4   c4 = *(const int4*)&col[e0];
        int4   r4 = *(const int4*)&row[e0];
        float4 w4 = *(const float4*)&w[e0];
        int ci, ri;
        ci = c4.x - base; if ((unsigned)ci < RANGE) atomicAdd(&lc32[ci >> 1], 1u << ((ci & 1) * 16));
        ri = r4.x - base; if ((unsigned)ri < RANGE) atomicAdd(&ld[ri], w4.x);
        ci = c4.y - base; if ((unsigned)ci < RANGE) atomicAdd(&lc32[ci >> 1], 1u << ((ci & 1) * 16));
        ri = r4.y - base; if ((unsigned)ri < RANGE) atomicAdd(&ld[ri], w4.y);
        ci = c4.z - base; if ((unsigned)ci < RANGE) atomicAdd(&lc32[ci >> 1], 1u << ((ci & 1) * 16));
        ri = r4.z - base; if ((unsigned)ri < RANGE) atomicAdd(&ld[ri], w4.z);
        ci = c4.w - base; if ((unsigned)ci < RANGE) atomicAdd(&lc32[ci >> 1], 1u << ((ci & 1) * 16));
        ri = r4.w - base; if ((unsigned)ri < RANGE) atomicAdd(&ld[ri], w4.w);
    }
    __syncthreads();
    unsigned short* pcb = pc + (size_t)blockIdx.x * RANGE;
    float*          pdb = pd + (size_t)blockIdx.x * RANGE;
    for (int i = t; i < RANGE; i += HTHREADS) {
        pcb[i] = (unsigned short)((lc32[i >> 1] >> ((i & 1) * 16)) & 0xFFFFu);
        pdb[i] = ld[i];
    }
}

// ---- fold partials: dinv, cnt totals, per-slice exclusive prefix (pc in place) ----
__global__ __launch_bounds__(256) void reduce_kernel(
    unsigned short* __restrict__ pc, const float* __restrict__ pd,
    float* __restrict__ dinv, int* __restrict__ cnt)
{
    int n = blockIdx.x * 256 + threadIdx.x;
    if (n >= N_NODES) return;
    int r = n / RANGE, i = n - r * RANGE;
    size_t base = (size_t)r * BPR * RANGE + i;
    unsigned csum = 0; float d = 0.f;
    for (int b = 0; b < BPR; ++b) {
        size_t idx = base + (size_t)b * RANGE;
        unsigned x = pc[idx];
        pc[idx] = (unsigned short)csum;
        csum += x;
        d += pd[idx];
    }
    cnt[n] = (int)csum;
    dinv[n] = d > 0.f ? rsqrtf(d) : 0.f;
}

// ---- exclusive scan of cnt -> off, single 1024-thread block ----
__global__ __launch_bounds__(1024) void scan_kernel(
    const int* __restrict__ cnt, int* __restrict__ off)
{
    __shared__ int wsum[16];
    const int CH = (N_NODES + 1023) / 1024;   // 49
    int t = threadIdx.x;
    int lo = t * CH, hi = min(lo + CH, N_NODES);
    int s = 0;
    for (int i = lo; i < hi; ++i) s += cnt[i];
    int lane = t & 63, wid = t >> 6;
    int v = s;
    for (int d = 1; d < 64; d <<= 1) {
        int u = __shfl_up(v, d);
        if (lane >= d) v += u;
    }
    if (lane == 63) wsum[wid] = v;
    __syncthreads();
    if (t == 0) {
        int run = 0;
        for (int i = 0; i < 16; ++i) { int x = wsum[i]; wsum[i] = run; run += x; }
    }
    __syncthreads();
    int run = (v - s) + wsum[wid];
    for (int i = lo; i < hi; ++i) { off[i] = run; run += cnt[i]; }
    if (t == 1023) off[N_NODES] = run;
}

// ---- pass D: scatter via re-derived LDS ranks — zero global atomics ----
__global__ __launch_bounds__(HTHREADS) void scatter_part_kernel(
    const int* __restrict__ row, const int* __restrict__ col,
    const float* __restrict__ w, const float* __restrict__ dinv,
    const int* __restrict__ off, const unsigned short* __restrict__ pc,
    uint2* __restrict__ edges)
{
    __shared__ unsigned lc32[RANGE / 2];  // 12.5 KB
    int t = threadIdx.x;
    for (int i = t; i < RANGE / 2; i += HTHREADS) lc32[i] = 0u;
    __syncthreads();
    int r = blockIdx.x / BPR;
    int b = blockIdx.x % BPR;
    int base = r * RANGE;
    int lo = b * SLICE;
    const unsigned short* pcb = pc + (size_t)blockIdx.x * RANGE;
    for (int e0 = lo + t * 4; e0 < lo + SLICE; e0 += HTHREADS * 4) {
        int4   c4 = *(const int4*)&col[e0];
        int4   r4 = *(const int4*)&row[e0];
        float4 w4 = *(const float4*)&w[e0];
        #pragma unroll
        for (int j = 0; j < 4; ++j) {
            int c  = (j == 0) ? c4.x : (j == 1) ? c4.y : (j == 2) ? c4.z : c4.w;
            int rw = (j == 0) ? r4.x : (j == 1) ? r4.y : (j == 2) ? r4.z : r4.w;
            float we = (j == 0) ? w4.x : (j == 1) ? w4.y : (j == 2) ? w4.z : w4.w;
            int ci = c - base;
            if ((unsigned)ci < RANGE) {
                unsigned old = atomicAdd(&lc32[ci >> 1], 1u << ((ci & 1) * 16));
                unsigned lrank = (old >> ((ci & 1) * 16)) & 0xFFFFu;
                float nr = -dinv[rw] * we * dinv[c];
                int pos = off[c] + (int)pcb[ci] + (int)lrank;
                edges[pos] = make_uint2((unsigned)rw, __float_as_uint(nr));
            }
        }
    }
}

// ---- xf = relu(x @ W_in + b_in) -> f32 d_out tail AND fp16 T0 ----
__global__ __launch_bounds__(256) void xf_kernel(
    const float* __restrict__ x, const float* __restrict__ Win,
    const float* __restrict__ bin, float* __restrict__ xf_out,
    __half* __restrict__ T0h)
{
    __shared__ float Ws[F_IN * EMB];   // 24576 B
    int t = threadIdx.x;
    for (int i = t; i < F_IN * EMB; i += 256) Ws[i] = Win[i];
    __syncthreads();
    int gid = blockIdx.x * 256 + t;
    if (gid >= N_NODES * EMB) return;
    int n = gid / EMB, j = gid - n * EMB;
    const float* xr = x + (size_t)n * F_IN;
    float acc = bin[j];
#pragma unroll 8
    for (int k = 0; k < F_IN; ++k) acc += xr[k] * Ws[k * EMB + j];
    acc = fmaxf(acc, 0.f);
    xf_out[gid] = acc;
    T0h[gid] = __float2half_rn(acc);
}

// ---- out_acc = T0 @ W0 (write, k=0 term; reads exact f32 xf) ----
__global__ __launch_bounds__(256) void gemm48_write_kernel(
    const float* __restrict__ T, const float* __restrict__ W,
    float* __restrict__ out)
{
    __shared__ float Ws[EMB * HID];
    int t = threadIdx.x;
    for (int i = t; i < EMB * HID; i += 256) Ws[i] = W[i];
    __syncthreads();
    int gid = blockIdx.x * 256 + t;
    if (gid >= N_NODES * HID) return;
    int n = gid / HID, j = gid - n * HID;
    const float* tr = T + (size_t)n * EMB;
    float acc = 0.f;
#pragma unroll 8
    for (int c = 0; c < EMB; ++c) acc += tr[c] * Ws[c * HID + j];
    out[gid] = acc;
}

// ---- fused: T_k = prop (or 2*prop - tprev) in fp16, out_acc += T_k @ W_k ----
__global__ __launch_bounds__(256) void prop_fused_kernel(
    const int* __restrict__ off, const uint2* __restrict__ edges,
    const __half* __restrict__ tsrc, const __half* __restrict__ tprev,
    __half* __restrict__ tdst, const float* __restrict__ Wk,
    float* __restrict__ out_acc, int cheb_mode)
{
    __shared__ float Ws[EMB * HID];     // 9216 B
    __shared__ float tdS[16][EMB + 1];
    int t = threadIdx.x;
    for (int i = t; i < EMB * HID; i += 256) Ws[i] = Wk[i];

    int grp = t >> 4, lane = t & 15;
    int g = blockIdx.x * 16 + grp;

    float a0 = 0.f, a1 = 0.f, a2 = 0.f;
    int s = off[g], e = off[g + 1];
    int p = s;
    int e4 = s + ((e - s) & ~3);
    for (; p < e4; p += 4) {
        uint2 er0 = edges[p],     er1 = edges[p + 1];
        uint2 er2 = edges[p + 2], er3 = edges[p + 3];
        const __half* t0 = tsrc + (size_t)er0.x * EMB;
        const __half* t1 = tsrc + (size_t)er1.x * EMB;
        const __half* t2 = tsrc + (size_t)er2.x * EMB;
        const __half* t3 = tsrc + (size_t)er3.x * EMB;
        float w0 = __uint_as_float(er0.y), w1 = __uint_as_float(er1.y);
        float w2 = __uint_as_float(er2.y), w3 = __uint_as_float(er3.y);
        float v00 = __half2float(t0[lane]);
        float v01 = __half2float(t0[lane + 16]);
        float v02 = __half2float(t0[lane + 32]);
        float v10 = __half2float(t1[lane]);
        float v11 = __half2float(t1[lane + 16]);
        float v12 = __half2float(t1[lane + 32]);
        float v20 = __half2float(t2[lane]);
        float v21 = __half2float(t2[lane + 16]);
        float v22 = __half2float(t2[lane + 32]);
        float v30 = __half2float(t3[lane]);
        float v31 = __half2float(t3[lane + 16]);
        float v32 = __half2float(t3[lane + 32]);
        a0 += w0 * v00; a1 += w0 * v01; a2 += w0 * v02;
        a0 += w1 * v10; a1 += w1 * v11; a2 += w1 * v12;
        a0 += w2 * v20; a1 += w2 * v21; a2 += w2 * v22;
        a0 += w3 * v30; a1 += w3 * v31; a2 += w3 * v32;
    }
    for (; p < e; ++p) {
        uint2 er = edges[p];
        float wv = __uint_as_float(er.y);
        const __half* tr = tsrc + (size_t)er.x * EMB;
        a0 += wv * __half2float(tr[lane]);
        a1 += wv * __half2float(tr[lane + 16]);
        a2 += wv * __half2float(tr[lane + 32]);
    }
    if (cheb_mode) {
        const __half* tp = tprev + (size_t)g * EMB;
        a0 = 2.f * a0 - __half2float(tp[lane]);
        a1 = 2.f * a1 - __half2float(tp[lane + 16]);
        a2 = 2.f * a2 - __half2float(tp[lane + 32]);
    }
    __half* td = tdst + (size_t)g * EMB;
    td[lane]      = __float2half_rn(a0);
    td[lane + 16] = __float2half_rn(a1);
    td[lane + 32] = __float2half_rn(a2);
    tdS[grp][lane]      = a0;
    tdS[grp][lane + 16] = a1;
    tdS[grp][lane + 32] = a2;
    __syncthreads();

    float o0 = 0.f, o1 = 0.f, o2 = 0.f;
#pragma unroll 8
    for (int c = 0; c < EMB; ++c) {
        float tv = tdS[grp][c];
        o0 += tv * Ws[c * HID + lane];
        o1 += tv * Ws[c * HID + lane + 16];
        o2 += tv * Ws[c * HID + lane + 32];
    }
    float* orow = out_acc + (size_t)g * HID;
    orow[lane]      += o0;
    orow[lane + 16] += o1;
    orow[lane + 32] += o2;
}

// ---- y = relu(out_acc + b_cheb) @ W_out + b_out ----
__global__ __launch_bounds__(256) void final_kernel(
    const float* __restrict__ out_acc, const float* __restrict__ bch,
    const float* __restrict__ Wout, const float* __restrict__ bout,
    float* __restrict__ y)
{
    __shared__ float Ws[HID * OUTF];
    __shared__ float bs[HID];
    int t = threadIdx.x;
    for (int i = t; i < HID * OUTF; i += 256) Ws[i] = Wout[i];
    if (t < HID) bs[t] = bch[t];
    __syncthreads();
    int gid = blockIdx.x * 256 + t;
    if (gid >= N_NODES * OUTF) return;
    int n = gid / OUTF, o = gid - n * OUTF;
    const float* orow = out_acc + (size_t)n * HID;
    float acc = bout[o];
#pragma unroll 8
    for (int h = 0; h < HID; ++h) {
        float v = fmaxf(orow[h] + bs[h], 0.f);
        acc += v * Ws[h * OUTF + o];
    }
    y[gid] = acc;
}

extern "C" void kernel_launch(void* const* d_in, const int* in_sizes, int n_in,
                              void* d_out, int out_size, void* d_ws, size_t ws_size,
                              hipStream_t stream)
{
    const float* x    = (const float*)d_in[0];
    const int*   ei   = (const int*)d_in[1];
    const float* ew   = (const float*)d_in[2];
    const float* Win  = (const float*)d_in[3];
    const float* bin  = (const float*)d_in[4];
    const float* Wch  = (const float*)d_in[5];   // [7,48,48]
    const float* bch  = (const float*)d_in[6];
    const float* Wout = (const float*)d_in[7];
    const float* bout = (const float*)d_in[8];

    const int* row = ei;
    const int* col = ei + N_EDGES;

    float* y_out  = (float*)d_out;                           // [N,64]
    float* xf_out = (float*)d_out + (size_t)N_NODES * OUTF;  // [N,48]

    // ---- workspace carve (256B aligned); every buffer fully written before read ----
    char* p = (char*)d_ws;
    auto carve = [&](size_t bytes) {
        void* q = p;
        p += (bytes + 255) & ~(size_t)255;
        return q;
    };
    unsigned short* pc = (unsigned short*)carve((size_t)NR * BPR * RANGE * 2); // 6.4 MB
    float*    pd  = (float*)carve((size_t)NR * BPR * RANGE * 4);               // 12.8 MB
    float*    dinv = (float*)carve(N_NODES * 4);
    int*      cnt  = (int*)  carve(N_NODES * 4);
    int*      off  = (int*)  carve((N_NODES + 1) * 4);
    uint2*    edges = (uint2*)carve((size_t)N_EDGES * 8);
    float*    out_acc = (float*)carve((size_t)N_NODES * HID * 4);
    __half*   T0h = (__half*)carve((size_t)N_NODES * EMB * 2);
    __half*   TAh = (__half*)carve((size_t)N_NODES * EMB * 2);
    __half*   TBh = (__half*)carve((size_t)N_NODES * EMB * 2);
    __half*   TCh = (__half*)carve((size_t)N_NODES * EMB * 2);

    // graph preprocessing — zero global atomics, vec4 edge reads
    hist_part_kernel<<<NR * BPR, HTHREADS, 0, stream>>>(row, col, ew, pc, pd);
    reduce_kernel<<<(N_NODES + 255) / 256, 256, 0, stream>>>(pc, pd, dinv, cnt);
    scan_kernel<<<1, 1024, 0, stream>>>(cnt, off);
    scatter_part_kernel<<<NR * BPR, HTHREADS, 0, stream>>>(row, col, ew, dinv, off, pc, edges);

    // xf = relu(x @ W_in + b_in) -> f32 d_out tail + fp16 T0
    xf_kernel<<<(N_NODES * EMB + 255) / 256, 256, 0, stream>>>(x, Win, bin, xf_out, T0h);

    // out_acc = T0 @ W0 (exact f32)
    gemm48_write_kernel<<<(N_NODES * HID + 255) / 256, 256, 0, stream>>>(xf_out, Wch, out_acc);

    const int prop_grid = N_NODES / 16;   // 3125, exact

    // T1 = prop(T0); out_acc += T1 @ W1
    prop_fused_kernel<<<prop_grid, 256, 0, stream>>>(off, edges, T0h, nullptr,
                                                     TAh, Wch + EMB * HID, out_acc, 0);
    // Chebyshev recursion with fused GEMM — proven 3-buffer rotation.
    const __half* A = T0h;  // T_{k-2}
    __half*       B = TAh;  // T_{k-1}
    __half* bufs[3] = {TBh, TCh, TAh};
    for (int k = 2; k < KCH; ++k) {
        __half* C = bufs[(k - 2) % 3];
        prop_fused_kernel<<<prop_grid, 256, 0, stream>>>(off, edges, B, A,
                                                         C, Wch + (size_t)k * EMB * HID, out_acc, 1);
        A = B; B = C;
    }

    // y = relu(out_acc + b_cheb) @ W_out + b_out
    final_kernel<<<(N_NODES * OUTF + 255) / 256, 256, 0, stream>>>(out_acc, bch, Wout, bout, y_out);
}

// Round 8
// 413.539 us; speedup vs baseline: 2.3102x; 1.1509x over previous
//
#include <hip/hip_runtime.h>
#include <hip/hip_fp16.h>

#define N_NODES 50000
#define N_EDGES 1600000
#define F_IN    128
#define EMB     48
#define HID     48
#define OUTF    64
#define KCH     7

#define NR    8                      // node ranges (LDS partitions)
#define RANGE (N_NODES / NR)         // 6250 counters
#define BPR   64                     // edge slices
#define SLICE (N_EDGES / BPR)        // 25000 edges per slice (div by 4)
#define HTHREADS 512
#define NBLK  ((N_NODES + 255) / 256)   // 196 reduce blocks

// ---- pass A: partitioned LDS histogram (cnt by col packed u16, deg by row f32) ----
__global__ __launch_bounds__(HTHREADS) void hist_part_kernel(
    const int* __restrict__ row, const int* __restrict__ col,
    const float* __restrict__ w,
    unsigned short* __restrict__ pc, float* __restrict__ pd)
{
    __shared__ unsigned lc32[RANGE / 2];  // 12.5 KB, 2 u16 counters per word
    __shared__ float    ld[RANGE];        // 25 KB
    int t = threadIdx.x;
    for (int i = t; i < RANGE / 2; i += HTHREADS) lc32[i] = 0u;
    for (int i = t; i < RANGE; i += HTHREADS) ld[i] = 0.f;
    __syncthreads();
    int r = blockIdx.x / BPR;        // node range
    int b = blockIdx.x % BPR;        // edge slice
    int base = r * RANGE;
    int lo = b * SLICE;
    for (int e0 = lo + t * 4; e0 < lo + SLICE; e0 += HTHREADS * 4) {
        int4   c4 = *(const int4*)&col[e0];
        int4   r4 = *(const int4*)&row[e0];
        float4 w4 = *(const float4*)&w[e0];
        int ci, ri;
        ci = c4.x - base; if ((unsigned)ci < RANGE) atomicAdd(&lc32[ci >> 1], 1u << ((ci & 1) * 16));
        ri = r4.x - base; if ((unsigned)ri < RANGE) atomicAdd(&ld[ri], w4.x);
        ci = c4.y - base; if ((unsigned)ci < RANGE) atomicAdd(&lc32[ci >> 1], 1u << ((ci & 1) * 16));
        ri = r4.y - base; if ((unsigned)ri < RANGE) atomicAdd(&ld[ri], w4.y);
        ci = c4.z - base; if ((unsigned)ci < RANGE) atomicAdd(&lc32[ci >> 1], 1u << ((ci & 1) * 16));
        ri = r4.z - base; if ((unsigned)ri < RANGE) atomicAdd(&ld[ri], w4.z);
        ci = c4.w - base; if ((unsigned)ci < RANGE) atomicAdd(&lc32[ci >> 1], 1u << ((ci & 1) * 16));
        ri = r4.w - base; if ((unsigned)ri < RANGE) atomicAdd(&ld[ri], w4.w);
    }
    __syncthreads();
    unsigned short* pcb = pc + (size_t)blockIdx.x * RANGE;
    float*          pdb = pd + (size_t)blockIdx.x * RANGE;
    for (int i = t; i < RANGE; i += HTHREADS) {
        pcb[i] = (unsigned short)((lc32[i >> 1] >> ((i & 1) * 16)) & 0xFFFFu);
        pdb[i] = ld[i];
    }
}

// ---- fold partials: dinv, per-slice prefix (pc in place), AND intra-block
//      exclusive scan of node counts -> off (local), block totals -> bsum ----
__global__ __launch_bounds__(256) void reduce_kernel(
    unsigned short* __restrict__ pc, const float* __restrict__ pd,
    float* __restrict__ dinv, int* __restrict__ off, int* __restrict__ bsum)
{
    int t = threadIdx.x;
    int n = blockIdx.x * 256 + t;
    int c = 0; float d = 0.f;
    if (n < N_NODES) {
        int r = n / RANGE, i = n - r * RANGE;
        size_t base = (size_t)r * BPR * RANGE + i;
        unsigned csum = 0;
        for (int b = 0; b < BPR; ++b) {
            size_t idx = base + (size_t)b * RANGE;
            unsigned x = pc[idx];
            pc[idx] = (unsigned short)csum;
            csum += x;
            d += pd[idx];
        }
        c = (int)csum;
        dinv[n] = d > 0.f ? rsqrtf(d) : 0.f;
    }
    // intra-block exclusive scan of c
    int lane = t & 63, wid = t >> 6;
    int v = c;
    for (int s = 1; s < 64; s <<= 1) {
        int u = __shfl_up(v, s);
        if (lane >= s) v += u;
    }
    __shared__ int ws[4];
    if (lane == 63) ws[wid] = v;
    __syncthreads();
    int wb = 0;
    for (int i = 0; i < 4; ++i) if (i < wid) wb += ws[i];
    int ex = (v - c) + wb;
    if (n < N_NODES) off[n] = ex;
    if (t == 255) bsum[blockIdx.x] = ex + c;
}

// ---- exclusive scan of 196 block sums (tiny, 1 block) ----
__global__ __launch_bounds__(256) void bsum_scan_kernel(
    int* __restrict__ bsum, int* __restrict__ off)
{
    int t = threadIdx.x;
    int orig = (t < NBLK) ? bsum[t] : 0;
    int lane = t & 63, wid = t >> 6;
    int v = orig;
    for (int s = 1; s < 64; s <<= 1) {
        int u = __shfl_up(v, s);
        if (lane >= s) v += u;
    }
    __shared__ int ws[4];
    if (lane == 63) ws[wid] = v;
    __syncthreads();
    int wb = 0;
    for (int i = 0; i < 4; ++i) if (i < wid) wb += ws[i];
    int ex = (v - orig) + wb;
    if (t < NBLK) bsum[t] = ex;
    if (t == NBLK - 1) off[N_NODES] = ex + orig;
}

// ---- add block prefix back: off[n] += bsum[n/256] ----
__global__ __launch_bounds__(256) void add_off_kernel(
    int* __restrict__ off, const int* __restrict__ bsum)
{
    int n = blockIdx.x * 256 + threadIdx.x;
    if (n < N_NODES) off[n] += bsum[n >> 8];
}

// ---- pass D: scatter via re-derived LDS ranks — zero global atomics ----
__global__ __launch_bounds__(HTHREADS) void scatter_part_kernel(
    const int* __restrict__ row, const int* __restrict__ col,
    const float* __restrict__ w, const float* __restrict__ dinv,
    const int* __restrict__ off, const unsigned short* __restrict__ pc,
    uint2* __restrict__ edges)
{
    __shared__ unsigned lc32[RANGE / 2];  // 12.5 KB
    int t = threadIdx.x;
    for (int i = t; i < RANGE / 2; i += HTHREADS) lc32[i] = 0u;
    __syncthreads();
    int r = blockIdx.x / BPR;
    int b = blockIdx.x % BPR;
    int base = r * RANGE;
    int lo = b * SLICE;
    const unsigned short* pcb = pc + (size_t)blockIdx.x * RANGE;
    for (int e0 = lo + t * 4; e0 < lo + SLICE; e0 += HTHREADS * 4) {
        int4   c4 = *(const int4*)&col[e0];
        int4   r4 = *(const int4*)&row[e0];
        float4 w4 = *(const float4*)&w[e0];
        #pragma unroll
        for (int j = 0; j < 4; ++j) {
            int c  = (j == 0) ? c4.x : (j == 1) ? c4.y : (j == 2) ? c4.z : c4.w;
            int rw = (j == 0) ? r4.x : (j == 1) ? r4.y : (j == 2) ? r4.z : r4.w;
            float we = (j == 0) ? w4.x : (j == 1) ? w4.y : (j == 2) ? w4.z : w4.w;
            int ci = c - base;
            if ((unsigned)ci < RANGE) {
                unsigned old = atomicAdd(&lc32[ci >> 1], 1u << ((ci & 1) * 16));
                unsigned lrank = (old >> ((ci & 1) * 16)) & 0xFFFFu;
                float nr = -dinv[rw] * we * dinv[c];
                int pos = off[c] + (int)pcb[ci] + (int)lrank;
                edges[pos] = make_uint2((unsigned)rw, __float_as_uint(nr));
            }
        }
    }
}

// ---- xf = relu(x @ W_in + b_in) -> f32 d_out tail AND fp16 T0 ----
__global__ __launch_bounds__(256) void xf_kernel(
    const float* __restrict__ x, const float* __restrict__ Win,
    const float* __restrict__ bin, float* __restrict__ xf_out,
    __half* __restrict__ T0h)
{
    __shared__ float Ws[F_IN * EMB];   // 24576 B
    int t = threadIdx.x;
    for (int i = t; i < F_IN * EMB; i += 256) Ws[i] = Win[i];
    __syncthreads();
    int gid = blockIdx.x * 256 + t;
    if (gid >= N_NODES * EMB) return;
    int n = gid / EMB, j = gid - n * EMB;
    const float* xr = x + (size_t)n * F_IN;
    float acc = bin[j];
#pragma unroll 8
    for (int k = 0; k < F_IN; ++k) acc += xr[k] * Ws[k * EMB + j];
    acc = fmaxf(acc, 0.f);
    xf_out[gid] = acc;
    T0h[gid] = __float2half_rn(acc);
}

// ---- out_acc = T0 @ W0 (write, k=0 term; reads exact f32 xf) ----
__global__ __launch_bounds__(256) void gemm48_write_kernel(
    const float* __restrict__ T, const float* __restrict__ W,
    float* __restrict__ out)
{
    __shared__ float Ws[EMB * HID];
    int t = threadIdx.x;
    for (int i = t; i < EMB * HID; i += 256) Ws[i] = W[i];
    __syncthreads();
    int gid = blockIdx.x * 256 + t;
    if (gid >= N_NODES * HID) return;
    int n = gid / HID, j = gid - n * HID;
    const float* tr = T + (size_t)n * EMB;
    float acc = 0.f;
#pragma unroll 8
    for (int c = 0; c < EMB; ++c) acc += tr[c] * Ws[c * HID + j];
    out[gid] = acc;
}

// ---- fused: T_k = prop (or 2*prop - tprev) in fp16, out_acc += T_k @ W_k ----
// 16 lanes/node; edge loop unrolled x8 (24 outstanding gathers), static indices.
__global__ __launch_bounds__(256) void prop_fused_kernel(
    const int* __restrict__ off, const uint2* __restrict__ edges,
    const __half* __restrict__ tsrc, const __half* __restrict__ tprev,
    __half* __restrict__ tdst, const float* __restrict__ Wk,
    float* __restrict__ out_acc, int cheb_mode)
{
    __shared__ float Ws[EMB * HID];     // 9216 B
    __shared__ float tdS[16][EMB + 1];
    int t = threadIdx.x;
    for (int i = t; i < EMB * HID; i += 256) Ws[i] = Wk[i];

    int grp = t >> 4, lane = t & 15;
    int g = blockIdx.x * 16 + grp;

    float a0 = 0.f, a1 = 0.f, a2 = 0.f;
    int s = off[g], e = off[g + 1];
    int p = s;
    int e8 = s + ((e - s) & ~7);
    for (; p < e8; p += 8) {
        uint2 er[8];
        #pragma unroll
        for (int j = 0; j < 8; ++j) er[j] = edges[p + j];
        float ww[8], v0[8], v1[8], v2[8];
        #pragma unroll
        for (int j = 0; j < 8; ++j) {
            const __half* tj = tsrc + (size_t)er[j].x * EMB;
            ww[j] = __uint_as_float(er[j].y);
            v0[j] = __half2float(tj[lane]);
            v1[j] = __half2float(tj[lane + 16]);
            v2[j] = __half2float(tj[lane + 32]);
        }
        #pragma unroll
        for (int j = 0; j < 8; ++j) {
            a0 += ww[j] * v0[j];
            a1 += ww[j] * v1[j];
            a2 += ww[j] * v2[j];
        }
    }
    for (; p < e; ++p) {
        uint2 er = edges[p];
        float wv = __uint_as_float(er.y);
        const __half* tr = tsrc + (size_t)er.x * EMB;
        a0 += wv * __half2float(tr[lane]);
        a1 += wv * __half2float(tr[lane + 16]);
        a2 += wv * __half2float(tr[lane + 32]);
    }
    if (cheb_mode) {
        const __half* tp = tprev + (size_t)g * EMB;
        a0 = 2.f * a0 - __half2float(tp[lane]);
        a1 = 2.f * a1 - __half2float(tp[lane + 16]);
        a2 = 2.f * a2 - __half2float(tp[lane + 32]);
    }
    __half* td = tdst + (size_t)g * EMB;
    td[lane]      = __float2half_rn(a0);
    td[lane + 16] = __float2half_rn(a1);
    td[lane + 32] = __float2half_rn(a2);
    tdS[grp][lane]      = a0;
    tdS[grp][lane + 16] = a1;
    tdS[grp][lane + 32] = a2;
    __syncthreads();

    float o0 = 0.f, o1 = 0.f, o2 = 0.f;
#pragma unroll 8
    for (int c = 0; c < EMB; ++c) {
        float tv = tdS[grp][c];
        o0 += tv * Ws[c * HID + lane];
        o1 += tv * Ws[c * HID + lane + 16];
        o2 += tv * Ws[c * HID + lane + 32];
    }
    float* orow = out_acc + (size_t)g * HID;
    orow[lane]      += o0;
    orow[lane + 16] += o1;
    orow[lane + 32] += o2;
}

// ---- y = relu(out_acc + b_cheb) @ W_out + b_out ----
__global__ __launch_bounds__(256) void final_kernel(
    const float* __restrict__ out_acc, const float* __restrict__ bch,
    const float* __restrict__ Wout, const float* __restrict__ bout,
    float* __restrict__ y)
{
    __shared__ float Ws[HID * OUTF];
    __shared__ float bs[HID];
    int t = threadIdx.x;
    for (int i = t; i < HID * OUTF; i += 256) Ws[i] = Wout[i];
    if (t < HID) bs[t] = bch[t];
    __syncthreads();
    int gid = blockIdx.x * 256 + t;
    if (gid >= N_NODES * OUTF) return;
    int n = gid / OUTF, o = gid - n * OUTF;
    const float* orow = out_acc + (size_t)n * HID;
    float acc = bout[o];
#pragma unroll 8
    for (int h = 0; h < HID; ++h) {
        float v = fmaxf(orow[h] + bs[h], 0.f);
        acc += v * Ws[h * OUTF + o];
    }
    y[gid] = acc;
}

extern "C" void kernel_launch(void* const* d_in, const int* in_sizes, int n_in,
                              void* d_out, int out_size, void* d_ws, size_t ws_size,
                              hipStream_t stream)
{
    const float* x    = (const float*)d_in[0];
    const int*   ei   = (const int*)d_in[1];
    const float* ew   = (const float*)d_in[2];
    const float* Win  = (const float*)d_in[3];
    const float* bin  = (const float*)d_in[4];
    const float* Wch  = (const float*)d_in[5];   // [7,48,48]
    const float* bch  = (const float*)d_in[6];
    const float* Wout = (const float*)d_in[7];
    const float* bout = (const float*)d_in[8];

    const int* row = ei;
    const int* col = ei + N_EDGES;

    float* y_out  = (float*)d_out;                           // [N,64]
    float* xf_out = (float*)d_out + (size_t)N_NODES * OUTF;  // [N,48]

    // ---- workspace carve (256B aligned); every buffer fully written before read ----
    char* p = (char*)d_ws;
    auto carve = [&](size_t bytes) {
        void* q = p;
        p += (bytes + 255) & ~(size_t)255;
        return q;
    };
    unsigned short* pc = (unsigned short*)carve((size_t)NR * BPR * RANGE * 2); // 6.4 MB
    float*    pd  = (float*)carve((size_t)NR * BPR * RANGE * 4);               // 12.8 MB
    float*    dinv = (float*)carve(N_NODES * 4);
    int*      off  = (int*)  carve((N_NODES + 1) * 4);
    int*      bsum = (int*)  carve(NBLK * 4);
    uint2*    edges = (uint2*)carve((size_t)N_EDGES * 8);
    float*    out_acc = (float*)carve((size_t)N_NODES * HID * 4);
    __half*   T0h = (__half*)carve((size_t)N_NODES * EMB * 2);
    __half*   TAh = (__half*)carve((size_t)N_NODES * EMB * 2);
    __half*   TBh = (__half*)carve((size_t)N_NODES * EMB * 2);
    __half*   TCh = (__half*)carve((size_t)N_NODES * EMB * 2);

    // graph preprocessing — zero global atomics, hierarchical scan
    hist_part_kernel<<<NR * BPR, HTHREADS, 0, stream>>>(row, col, ew, pc, pd);
    reduce_kernel<<<NBLK, 256, 0, stream>>>(pc, pd, dinv, off, bsum);
    bsum_scan_kernel<<<1, 256, 0, stream>>>(bsum, off);
    add_off_kernel<<<NBLK, 256, 0, stream>>>(off, bsum);
    scatter_part_kernel<<<NR * BPR, HTHREADS, 0, stream>>>(row, col, ew, dinv, off, pc, edges);

    // xf = relu(x @ W_in + b_in) -> f32 d_out tail + fp16 T0
    xf_kernel<<<(N_NODES * EMB + 255) / 256, 256, 0, stream>>>(x, Win, bin, xf_out, T0h);

    // out_acc = T0 @ W0 (exact f32)
    gemm48_write_kernel<<<(N_NODES * HID + 255) / 256, 256, 0, stream>>>(xf_out, Wch, out_acc);

    const int prop_grid = N_NODES / 16;   // 3125, exact

    // T1 = prop(T0); out_acc += T1 @ W1
    prop_fused_kernel<<<prop_grid, 256, 0, stream>>>(off, edges, T0h, nullptr,
                                                     TAh, Wch + EMB * HID, out_acc, 0);
    // Chebyshev recursion with fused GEMM — proven 3-buffer rotation.
    const __half* A = T0h;  // T_{k-2}
    __half*       B = TAh;  // T_{k-1}
    __half* bufs[3] = {TBh, TCh, TAh};
    for (int k = 2; k < KCH; ++k) {
        __half* C = bufs[(k - 2) % 3];
        prop_fused_kernel<<<prop_grid, 256, 0, stream>>>(off, edges, B, A,
                                                         C, Wch + (size_t)k * EMB * HID, out_acc, 1);
        A = B; B = C;
    }

    // y = relu(out_acc + b_cheb) @ W_out + b_out
    final_kernel<<<(N_NODES * OUTF + 255) / 256, 256, 0, stream>>>(out_acc, bch, Wout, bout, y_out);
}